// Round 1
// baseline (303.906 us; speedup 1.0000x reference)
//
#include <hip/hip_runtime.h>
#include <stdint.h>

#define B_ 4
#define T_ 1024
#define C_ 1024
#define H_ 16
#define D_ 64
#define M_ 4096   // B_*T_

typedef __attribute__((ext_vector_type(8))) short bf16x8;
typedef __attribute__((ext_vector_type(4))) float f32x4;
typedef __attribute__((ext_vector_type(4))) short short4v;

static __device__ __forceinline__ short f2bf(float f) {
  union { float f; unsigned u; } c; c.f = f;
  unsigned r = (c.u + 0x7fffu + ((c.u >> 16) & 1u)) >> 16;
  return (short)(unsigned short)r;
}

// async global->LDS, 16B per lane. LDS dest is wave-uniform base + lane*16.
static __device__ __forceinline__ void gl2lds16(const void* g, void* l) {
  __builtin_amdgcn_global_load_lds(
      (const __attribute__((address_space(1))) void*)(uintptr_t)g,
      (__attribute__((address_space(3))) void*)(uint32_t)(uintptr_t)l,
      16, 0, 0);
}

// ---------------- cast x -> bf16 ----------------
__global__ __launch_bounds__(256) void k_cast_x(const float* __restrict__ x,
                                                short* __restrict__ xb) {
  int i = blockIdx.x * 256 + threadIdx.x;      // 4 floats per thread
  float4 v = ((const float4*)x)[i];
  short4v o;
  o.x = f2bf(v.x); o.y = f2bf(v.y); o.z = f2bf(v.z); o.w = f2bf(v.w);
  ((short4v*)xb)[i] = o;
}

// ---------------- transpose-cast W[K][N] -> Wt[N][K] bf16 ----------------
__global__ void k_transpose_w(const float* __restrict__ Wq, const float* __restrict__ Wk,
                              const float* __restrict__ Wv, const float* __restrict__ Wo,
                              short* __restrict__ Wt) {
  __shared__ float t[32][33];
  const float* W = (blockIdx.z == 0) ? Wq : (blockIdx.z == 1) ? Wk
                   : (blockIdx.z == 2) ? Wv : Wo;
  short* out = Wt + (size_t)blockIdx.z * C_ * C_;
  int n0 = blockIdx.x * 32, k0 = blockIdx.y * 32;
  int tx = threadIdx.x, ty = threadIdx.y;
#pragma unroll
  for (int i = 0; i < 4; i++)
    t[ty + 8*i][tx] = W[(size_t)(k0 + ty + 8*i) * C_ + n0 + tx];
  __syncthreads();
#pragma unroll
  for (int i = 0; i < 4; i++)
    out[(size_t)(n0 + ty + 8*i) * C_ + k0 + tx] = f2bf(t[tx][ty + 8*i]);
}

// ---------------- shared bt-GEMM body: C[128x128] tile, BK=64 ----------------
// A [M,1024] bf16 row-major, Bt [N=1024,1024] bf16 row-major (i.e. B^T).
// XOR-swizzled LDS: chunk_stored = chunk ^ (row&7); global side scatters to match.
static __device__ __forceinline__ void gemm_body(const short* __restrict__ A,
                                                 const short* __restrict__ Bt,
                                                 short* sA, short* sB,
                                                 f32x4 acc[4][4]) {
  const int tid = threadIdx.x;
  const int w = tid >> 6, lane = tid & 63;
  const int quad = lane >> 4, l16 = lane & 15;
  const int m0 = blockIdx.y * 128, n0 = blockIdx.x * 128;
  const int wm = (w >> 1) * 64, wn = (w & 1) * 64;
  const int srow = lane >> 3;          // row within 8-row chunk
  const int sch = lane & 7;            // stored 16B-chunk within row

#pragma unroll
  for (int mt = 0; mt < 4; mt++)
#pragma unroll
    for (int nt = 0; nt < 4; nt++)
#pragma unroll
      for (int e = 0; e < 4; e++) acc[mt][nt][e] = 0.f;

  for (int k0 = 0; k0 < C_; k0 += 64) {
    __syncthreads();
#pragma unroll
    for (int i = 0; i < 4; i++) {
      int c = w * 4 + i;               // 16 chunks of 1KB, 4 per wave
      int row = c * 8 + srow;
      int ch = sch ^ (row & 7);        // data chunk that lands at stored slot
      gl2lds16(&A[(size_t)(m0 + row) * C_ + k0 + ch * 8], &sA[c * 512]);
      gl2lds16(&Bt[(size_t)(n0 + row) * C_ + k0 + ch * 8], &sB[c * 512]);
    }
    __syncthreads();
#pragma unroll
    for (int ks = 0; ks < 2; ks++) {
      bf16x8 af[4], bfv[4];
      int chq = ks * 4 + quad;
#pragma unroll
      for (int t4 = 0; t4 < 4; t4++) {
        int rowa = wm + t4 * 16 + l16;
        af[t4] = *(const bf16x8*)&sA[rowa * 64 + (chq ^ (rowa & 7)) * 8];
        int rowb = wn + t4 * 16 + l16;
        bfv[t4] = *(const bf16x8*)&sB[rowb * 64 + (chq ^ (rowb & 7)) * 8];
      }
#pragma unroll
      for (int mt = 0; mt < 4; mt++)
#pragma unroll
        for (int nt = 0; nt < 4; nt++)
          acc[mt][nt] = __builtin_amdgcn_mfma_f32_16x16x32_bf16(
              af[mt], bfv[nt], acc[mt][nt], 0, 0, 0);
    }
  }
}

// ---------------- QKV projection (z = 0:Q, 1:K, 2:V-transposed) ----------------
__global__ __launch_bounds__(256) void k_qkv(
    const short* __restrict__ A, const short* __restrict__ WtAll,
    const float* __restrict__ bq, const float* __restrict__ bk,
    const float* __restrict__ bv,
    short* __restrict__ Qb, short* __restrict__ Kb, short* __restrict__ Vtb) {
  __shared__ short sA[8192];
  __shared__ short sB[8192];
  const int mode = blockIdx.z;
  const short* Bt = WtAll + (size_t)mode * C_ * C_;
  const float* bias = (mode == 0) ? bq : (mode == 1) ? bk : bv;
  f32x4 acc[4][4];
  gemm_body(A, Bt, sA, sB, acc);

  const int tid = threadIdx.x;
  const int w = tid >> 6, lane = tid & 63;
  const int quad = lane >> 4, l16 = lane & 15;
  const int m0 = blockIdx.y * 128, n0 = blockIdx.x * 128;
  const int wm = (w >> 1) * 64, wn = (w & 1) * 64;

#pragma unroll
  for (int mt = 0; mt < 4; mt++) {
#pragma unroll
    for (int nt = 0; nt < 4; nt++) {
      int ng = n0 + wn + nt * 16 + l16;
      float bval = bias[ng];
      int h = ng >> 6, d = ng & 63;
#pragma unroll
      for (int r = 0; r < 4; r++) {
        int mg = m0 + wm + mt * 16 + quad * 4 + r;
        int bb = mg >> 10, t = mg & 1023;
        short v16 = f2bf(acc[mt][nt][r] + bval);
        if (mode == 0)
          Qb[(((size_t)(bb * H_ + h) << 10) + t) * D_ + d] = v16;
        else if (mode == 1)
          Kb[(((size_t)(bb * H_ + h) << 10) + t) * D_ + d] = v16;
        else
          Vtb[(((size_t)(bb * H_ + h) * D_ + d) << 10) + t] = v16;
      }
    }
  }
}

// ---------------- output projection, fp32 out ----------------
__global__ __launch_bounds__(256) void k_proj(
    const short* __restrict__ A, const short* __restrict__ Bt,
    const float* __restrict__ bias, float* __restrict__ Y) {
  __shared__ short sA[8192];
  __shared__ short sB[8192];
  f32x4 acc[4][4];
  gemm_body(A, Bt, sA, sB, acc);

  const int tid = threadIdx.x;
  const int w = tid >> 6, lane = tid & 63;
  const int quad = lane >> 4, l16 = lane & 15;
  const int m0 = blockIdx.y * 128, n0 = blockIdx.x * 128;
  const int wm = (w >> 1) * 64, wn = (w & 1) * 64;

#pragma unroll
  for (int mt = 0; mt < 4; mt++)
#pragma unroll
    for (int nt = 0; nt < 4; nt++) {
      int ng = n0 + wn + nt * 16 + l16;
      float bval = bias[ng];
#pragma unroll
      for (int r = 0; r < 4; r++) {
        int mg = m0 + wm + mt * 16 + quad * 4 + r;
        Y[(size_t)mg * C_ + ng] = acc[mt][nt][r] + bval;
      }
    }
}

// ---------------- flash attention ----------------
// block = (128 q-rows, head, batch); 4 waves x 32 q-rows; K-tile = 128.
__global__ __launch_bounds__(256) void k_attn(
    const short* __restrict__ Qb, const short* __restrict__ Kb,
    const short* __restrict__ Vtb, const int* __restrict__ mask,
    short* __restrict__ Ob) {
  __shared__ short sU[17408];   // K-tile (128 x stride72) then P (4 waves x 32 x stride136)
  __shared__ short sV[8704];    // V^T tile: 64 x stride136
  const int tid = threadIdx.x;
  const int w = tid >> 6, lane = tid & 63;
  const int quad = lane >> 4, l16 = lane & 15;
  const int tq0 = blockIdx.x * 128;
  const int h = blockIdx.y, bb = blockIdx.z;
  const short* Qh = Qb + ((size_t)(bb * H_ + h) << 10) * D_;   // [t][d]
  const short* Kh = Kb + ((size_t)(bb * H_ + h) << 10) * D_;   // [t][d]
  const short* Vh = Vtb + (((size_t)(bb * H_ + h) * D_) << 10); // [d][t]
  const int* mrow = mask + bb * T_;

  // Q fragments: A-layout, rows w*32 + rt*16 + l16, k = ks*32 + quad*8
  bf16x8 aq[2][2];
#pragma unroll
  for (int rt = 0; rt < 2; rt++)
#pragma unroll
    for (int ks = 0; ks < 2; ks++)
      aq[rt][ks] = *(const bf16x8*)&Qh[(size_t)(tq0 + w * 32 + rt * 16 + l16) * D_ +
                                       ks * 32 + quad * 8];

  f32x4 o[2][4];
  float mR[2][4], lR[2][4];
#pragma unroll
  for (int rt = 0; rt < 2; rt++) {
#pragma unroll
    for (int nt = 0; nt < 4; nt++)
#pragma unroll
      for (int e = 0; e < 4; e++) o[rt][nt][e] = 0.f;
#pragma unroll
    for (int r = 0; r < 4; r++) { mR[rt][r] = -1e30f; lR[rt][r] = 0.f; }
  }

  for (int kt = 0; kt < T_; kt += 128) {
    __syncthreads();
    // stage K tile [128][64] -> sU stride 72 (pad 8 bf16: 2-way banks, 16B aligned rows)
#pragma unroll
    for (int i = 0; i < 4; i++) {
      int id = tid + 256 * i;
      int r = id >> 3, c = id & 7;
      *(int4*)&sU[r * 72 + c * 8] = *(const int4*)&Kh[(size_t)(kt + r) * D_ + c * 8];
    }
    // stage V^T tile [64][128] -> sV stride 136
#pragma unroll
    for (int i = 0; i < 4; i++) {
      int id = tid + 256 * i;
      int r = id >> 4, c = id & 15;
      *(int4*)&sV[r * 136 + c * 8] = *(const int4*)&Vh[((size_t)r << 10) + kt + c * 8];
    }
    __syncthreads();

    // S = Q K^T for this wave's 32 rows x 128 cols
    f32x4 s[2][8];
#pragma unroll
    for (int rt = 0; rt < 2; rt++)
#pragma unroll
      for (int ct = 0; ct < 8; ct++)
#pragma unroll
        for (int e = 0; e < 4; e++) s[rt][ct][e] = 0.f;

#pragma unroll
    for (int ks = 0; ks < 2; ks++)
#pragma unroll
      for (int ct = 0; ct < 8; ct++) {
        bf16x8 bk8 = *(const bf16x8*)&sU[(ct * 16 + l16) * 72 + ks * 32 + quad * 8];
        s[0][ct] = __builtin_amdgcn_mfma_f32_16x16x32_bf16(aq[0][ks], bk8, s[0][ct], 0, 0, 0);
        s[1][ct] = __builtin_amdgcn_mfma_f32_16x16x32_bf16(aq[1][ks], bk8, s[1][ct], 0, 0, 0);
      }

    float mb[8];
#pragma unroll
    for (int ct = 0; ct < 8; ct++)
      mb[ct] = mrow[kt + ct * 16 + l16] ? 0.f : -1e30f;

    // online softmax (C-layout: row = quad*4+r, col = ct*16+l16)
#pragma unroll
    for (int rt = 0; rt < 2; rt++)
#pragma unroll
      for (int r = 0; r < 4; r++) {
        float v = -1e30f;
#pragma unroll
        for (int ct = 0; ct < 8; ct++) {
          float sv = s[rt][ct][r] * 0.125f + mb[ct];
          s[rt][ct][r] = sv;
          v = fmaxf(v, sv);
        }
#pragma unroll
        for (int off = 1; off < 16; off <<= 1) v = fmaxf(v, __shfl_xor(v, off));
        float mnew = fmaxf(mR[rt][r], v);
        float alpha = __expf(mR[rt][r] - mnew);
        mR[rt][r] = mnew;
        float rs = 0.f;
#pragma unroll
        for (int ct = 0; ct < 8; ct++) {
          float p = __expf(s[rt][ct][r] - mnew);
          s[rt][ct][r] = p;
          rs += p;
        }
#pragma unroll
        for (int off = 1; off < 16; off <<= 1) rs += __shfl_xor(rs, off);
        lR[rt][r] = lR[rt][r] * alpha + rs;
#pragma unroll
        for (int nt = 0; nt < 4; nt++) o[rt][nt][r] *= alpha;
      }

    __syncthreads();   // all waves done reading sU-as-K before P overwrites it
    short* Pw = &sU[w * 32 * 136];   // per-wave private region
#pragma unroll
    for (int rt = 0; rt < 2; rt++)
#pragma unroll
      for (int ct = 0; ct < 8; ct++)
#pragma unroll
        for (int r = 0; r < 4; r++)
          Pw[(rt * 16 + quad * 4 + r) * 136 + ct * 16 + l16] = f2bf(s[rt][ct][r]);

    // O += P V  (A = P from LDS in A-layout, B^T = V^T tile)
#pragma unroll
    for (int ks2 = 0; ks2 < 4; ks2++) {
      bf16x8 pa[2];
#pragma unroll
      for (int rt = 0; rt < 2; rt++)
        pa[rt] = *(const bf16x8*)&Pw[(rt * 16 + l16) * 136 + ks2 * 32 + quad * 8];
#pragma unroll
      for (int nt = 0; nt < 4; nt++) {
        bf16x8 bv8 = *(const bf16x8*)&sV[(nt * 16 + l16) * 136 + ks2 * 32 + quad * 8];
        o[0][nt] = __builtin_amdgcn_mfma_f32_16x16x32_bf16(pa[0], bv8, o[0][nt], 0, 0, 0);
        o[1][nt] = __builtin_amdgcn_mfma_f32_16x16x32_bf16(pa[1], bv8, o[1][nt], 0, 0, 0);
      }
    }
  }

  // epilogue: O / l -> Ob [4096][1024] bf16 (row-major for out-proj A)
#pragma unroll
  for (int rt = 0; rt < 2; rt++)
#pragma unroll
    for (int r = 0; r < 4; r++) {
      float inv = 1.f / lR[rt][r];
      int tg = tq0 + w * 32 + rt * 16 + quad * 4 + r;
#pragma unroll
      for (int nt = 0; nt < 4; nt++) {
        int col = h * D_ + nt * 16 + l16;
        Ob[(size_t)(bb * T_ + tg) * C_ + col] = f2bf(o[rt][nt][r] * inv);
      }
    }
}

// ---------------- in-place LayerNorm over rows of 1024 ----------------
__global__ __launch_bounds__(256) void k_ln(float* __restrict__ Y,
                                            const float* __restrict__ g,
                                            const float* __restrict__ b) {
  __shared__ float red[4], red2[4];
  const int row = blockIdx.x, tid = threadIdx.x;
  float4* yp = (float4*)(Y + (size_t)row * C_);
  float4 v = yp[tid];
  float sm = v.x + v.y + v.z + v.w;
#pragma unroll
  for (int off = 32; off; off >>= 1) sm += __shfl_xor(sm, off);
  if ((tid & 63) == 0) red[tid >> 6] = sm;
  __syncthreads();
  float mu = (red[0] + red[1] + red[2] + red[3]) * (1.f / C_);
  float dx = v.x - mu, dy = v.y - mu, dz = v.z - mu, dw = v.w - mu;
  float q = dx * dx + dy * dy + dz * dz + dw * dw;
#pragma unroll
  for (int off = 32; off; off >>= 1) q += __shfl_xor(q, off);
  if ((tid & 63) == 0) red2[tid >> 6] = q;
  __syncthreads();
  float var = (red2[0] + red2[1] + red2[2] + red2[3]) * (1.f / C_);
  float rsq = rsqrtf(var + 1e-5f);
  float4 gg = ((const float4*)g)[tid];
  float4 bb = ((const float4*)b)[tid];
  float4 out;
  out.x = dx * rsq * gg.x + bb.x;
  out.y = dy * rsq * gg.y + bb.y;
  out.z = dz * rsq * gg.z + bb.z;
  out.w = dw * rsq * gg.w + bb.w;
  yp[tid] = out;
}

extern "C" void kernel_launch(void* const* d_in, const int* in_sizes, int n_in,
                              void* d_out, int out_size, void* d_ws, size_t ws_size,
                              hipStream_t stream) {
  (void)in_sizes; (void)n_in; (void)out_size; (void)ws_size;
  const float* x    = (const float*)d_in[0];
  const int*   mask = (const int*)d_in[1];
  const float* Wq   = (const float*)d_in[2];
  const float* bq   = (const float*)d_in[3];
  const float* Wk   = (const float*)d_in[4];
  const float* bk   = (const float*)d_in[5];
  const float* Wv   = (const float*)d_in[6];
  const float* bv   = (const float*)d_in[7];
  const float* Wo   = (const float*)d_in[8];
  const float* bo   = (const float*)d_in[9];
  const float* lng  = (const float*)d_in[10];
  const float* lnb  = (const float*)d_in[11];

  char* ws = (char*)d_ws;
  short* xb  = (short*)(ws);                       // 8 MB, reused as Ob after QKV
  short* Wt  = (short*)(ws + ((size_t)8  << 20));  // 8 MB: Wq^T,Wk^T,Wv^T,Wo^T bf16
  short* Qb  = (short*)(ws + ((size_t)16 << 20));  // 8 MB  [B,H,T,D]
  short* Kb  = (short*)(ws + ((size_t)24 << 20));  // 8 MB  [B,H,T,D]
  short* Vtb = (short*)(ws + ((size_t)32 << 20));  // 8 MB  [B,H,D,T]
  short* Ob  = xb;                                 // alias: xb dead after QKV GEMMs
  float* Y   = (float*)d_out;

  k_cast_x<<<dim3(4096), dim3(256), 0, stream>>>(x, xb);
  k_transpose_w<<<dim3(32, 32, 4), dim3(32, 8), 0, stream>>>(Wq, Wk, Wv, Wo, Wt);
  k_qkv<<<dim3(8, 32, 3), dim3(256), 0, stream>>>(xb, Wt, bq, bk, bv, Qb, Kb, Vtb);
  k_attn<<<dim3(8, 16, 4), dim3(256), 0, stream>>>(Qb, Kb, Vtb, mask, Ob);
  k_proj<<<dim3(8, 32), dim3(256), 0, stream>>>(Ob, Wt + (size_t)3 * C_ * C_, bo, Y);
  k_ln<<<dim3(4096), dim3(256), 0, stream>>>(Y, lng, lnb);
}

// Round 2
// 299.957 us; speedup vs baseline: 1.0132x; 1.0132x over previous
//
#include <hip/hip_runtime.h>
#include <stdint.h>

#define B_ 4
#define T_ 1024
#define C_ 1024
#define H_ 16
#define D_ 64
#define M_ 4096   // B_*T_

typedef __attribute__((ext_vector_type(8))) short bf16x8;
typedef __attribute__((ext_vector_type(4))) float f32x4;
typedef __attribute__((ext_vector_type(4))) short short4v;

static __device__ __forceinline__ short f2bf(float f) {
  union { float f; unsigned u; } c; c.f = f;
  unsigned r = (c.u + 0x7fffu + ((c.u >> 16) & 1u)) >> 16;
  return (short)(unsigned short)r;
}

// async global->LDS, 16B per lane. LDS dest is wave-uniform base + lane*16.
static __device__ __forceinline__ void gl2lds16(const void* g, void* l) {
  __builtin_amdgcn_global_load_lds(
      (const __attribute__((address_space(1))) void*)(uintptr_t)g,
      (__attribute__((address_space(3))) void*)(uint32_t)(uintptr_t)l,
      16, 0, 0);
}

// ---------------- cast x -> bf16 ----------------
__global__ __launch_bounds__(256) void k_cast_x(const float* __restrict__ x,
                                                short* __restrict__ xb) {
  int i = blockIdx.x * 256 + threadIdx.x;      // 4 floats per thread
  float4 v = ((const float4*)x)[i];
  short4v o;
  o.x = f2bf(v.x); o.y = f2bf(v.y); o.z = f2bf(v.z); o.w = f2bf(v.w);
  ((short4v*)xb)[i] = o;
}

// ---------------- transpose-cast W[K][N] -> Wt[N][K] bf16 ----------------
__global__ void k_transpose_w(const float* __restrict__ Wq, const float* __restrict__ Wk,
                              const float* __restrict__ Wv, const float* __restrict__ Wo,
                              short* __restrict__ Wt) {
  __shared__ float t[32][33];
  const float* W = (blockIdx.z == 0) ? Wq : (blockIdx.z == 1) ? Wk
                   : (blockIdx.z == 2) ? Wv : Wo;
  short* out = Wt + (size_t)blockIdx.z * C_ * C_;
  int n0 = blockIdx.x * 32, k0 = blockIdx.y * 32;
  int tx = threadIdx.x, ty = threadIdx.y;
#pragma unroll
  for (int i = 0; i < 4; i++)
    t[ty + 8*i][tx] = W[(size_t)(k0 + ty + 8*i) * C_ + n0 + tx];
  __syncthreads();
#pragma unroll
  for (int i = 0; i < 4; i++)
    out[(size_t)(n0 + ty + 8*i) * C_ + k0 + tx] = f2bf(t[tx][ty + 8*i]);
}

// ---------------- shared bt-GEMM body: C[128x128] tile, BK=64 ----------------
static __device__ __forceinline__ void gemm_body(const short* __restrict__ A,
                                                 const short* __restrict__ Bt,
                                                 short* sA, short* sB,
                                                 f32x4 acc[4][4]) {
  const int tid = threadIdx.x;
  const int w = tid >> 6, lane = tid & 63;
  const int quad = lane >> 4, l16 = lane & 15;
  const int m0 = blockIdx.y * 128, n0 = blockIdx.x * 128;
  const int wm = (w >> 1) * 64, wn = (w & 1) * 64;
  const int srow = lane >> 3;          // row within 8-row chunk
  const int sch = lane & 7;            // stored 16B-chunk within row

#pragma unroll
  for (int mt = 0; mt < 4; mt++)
#pragma unroll
    for (int nt = 0; nt < 4; nt++)
#pragma unroll
      for (int e = 0; e < 4; e++) acc[mt][nt][e] = 0.f;

  for (int k0 = 0; k0 < C_; k0 += 64) {
    __syncthreads();
#pragma unroll
    for (int i = 0; i < 4; i++) {
      int c = w * 4 + i;               // 16 chunks of 1KB, 4 per wave
      int row = c * 8 + srow;
      int ch = sch ^ (row & 7);        // XOR swizzle
      gl2lds16(&A[(size_t)(m0 + row) * C_ + k0 + ch * 8], &sA[c * 512]);
      gl2lds16(&Bt[(size_t)(n0 + row) * C_ + k0 + ch * 8], &sB[c * 512]);
    }
    __syncthreads();
#pragma unroll
    for (int ks = 0; ks < 2; ks++) {
      bf16x8 af[4], bfv[4];
      int chq = ks * 4 + quad;
#pragma unroll
      for (int t4 = 0; t4 < 4; t4++) {
        int rowa = wm + t4 * 16 + l16;
        af[t4] = *(const bf16x8*)&sA[rowa * 64 + (chq ^ (rowa & 7)) * 8];
        int rowb = wn + t4 * 16 + l16;
        bfv[t4] = *(const bf16x8*)&sB[rowb * 64 + (chq ^ (rowb & 7)) * 8];
      }
#pragma unroll
      for (int mt = 0; mt < 4; mt++)
#pragma unroll
        for (int nt = 0; nt < 4; nt++)
          acc[mt][nt] = __builtin_amdgcn_mfma_f32_16x16x32_bf16(
              af[mt], bfv[nt], acc[mt][nt], 0, 0, 0);
    }
  }
}

// ---------------- QKV projection (z = 0:Q, 1:K, 2:V-transposed) ----------------
__global__ __launch_bounds__(256) void k_qkv(
    const short* __restrict__ A, const short* __restrict__ WtAll,
    const float* __restrict__ bq, const float* __restrict__ bk,
    const float* __restrict__ bv,
    short* __restrict__ Qb, short* __restrict__ Kb, short* __restrict__ Vtb) {
  __shared__ short sA[8192];
  __shared__ short sB[8192];
  const int mode = blockIdx.z;
  const short* Bt = WtAll + (size_t)mode * C_ * C_;
  const float* bias = (mode == 0) ? bq : (mode == 1) ? bk : bv;
  f32x4 acc[4][4];
  gemm_body(A, Bt, sA, sB, acc);

  const int tid = threadIdx.x;
  const int w = tid >> 6, lane = tid & 63;
  const int quad = lane >> 4, l16 = lane & 15;
  const int m0 = blockIdx.y * 128, n0 = blockIdx.x * 128;
  const int wm = (w >> 1) * 64, wn = (w & 1) * 64;

#pragma unroll
  for (int mt = 0; mt < 4; mt++) {
#pragma unroll
    for (int nt = 0; nt < 4; nt++) {
      int ng = n0 + wn + nt * 16 + l16;
      float bval = bias[ng];
      int h = ng >> 6, d = ng & 63;
#pragma unroll
      for (int r = 0; r < 4; r++) {
        int mg = m0 + wm + mt * 16 + quad * 4 + r;
        int bb = mg >> 10, t = mg & 1023;
        short v16 = f2bf(acc[mt][nt][r] + bval);
        if (mode == 0)
          Qb[(((size_t)(bb * H_ + h) << 10) + t) * D_ + d] = v16;
        else if (mode == 1)
          Kb[(((size_t)(bb * H_ + h) << 10) + t) * D_ + d] = v16;
        else
          Vtb[(((size_t)(bb * H_ + h) * D_ + d) << 10) + t] = v16;
      }
    }
  }
}

// ---------------- output projection, fp32 out ----------------
__global__ __launch_bounds__(256) void k_proj(
    const short* __restrict__ A, const short* __restrict__ Bt,
    const float* __restrict__ bias, float* __restrict__ Y) {
  __shared__ short sA[8192];
  __shared__ short sB[8192];
  f32x4 acc[4][4];
  gemm_body(A, Bt, sA, sB, acc);

  const int tid = threadIdx.x;
  const int w = tid >> 6, lane = tid & 63;
  const int quad = lane >> 4, l16 = lane & 15;
  const int m0 = blockIdx.y * 128, n0 = blockIdx.x * 128;
  const int wm = (w >> 1) * 64, wn = (w & 1) * 64;

#pragma unroll
  for (int mt = 0; mt < 4; mt++)
#pragma unroll
    for (int nt = 0; nt < 4; nt++) {
      int ng = n0 + wn + nt * 16 + l16;
      float bval = bias[ng];
#pragma unroll
      for (int r = 0; r < 4; r++) {
        int mg = m0 + wm + mt * 16 + quad * 4 + r;
        Y[(size_t)mg * C_ + ng] = acc[mt][nt][r] + bval;
      }
    }
}

// ---------------- flash attention, barrier-free ----------------
// block = (64 q-rows, head, batch); 4 waves x 16 q-rows; KV-tile = 128.
// Fixed-shift softmax (scores bounded, no running max), per-lane deferred
// row-sum, K/V fragments straight from global (L2-resident), LDS only for
// the per-wave P C->A layout transpose. No __syncthreads anywhere.
#define PSTRIDE 136   // shorts; 272B = 17 cachelines, 16B-aligned rows
__global__ __launch_bounds__(256, 4) void k_attn(
    const short* __restrict__ Qb, const short* __restrict__ Kb,
    const short* __restrict__ Vtb, const int* __restrict__ mask,
    short* __restrict__ Ob) {
  __shared__ short sP[4 * 16 * PSTRIDE];
  const int tid = threadIdx.x;
  const int w = tid >> 6, lane = tid & 63;
  const int quad = lane >> 4, l16 = lane & 15;
  const int tq0 = blockIdx.x * 64 + w * 16;
  const int h = blockIdx.y, bb = blockIdx.z;
  const short* Qh = Qb + ((size_t)(bb * H_ + h) << 10) * D_;    // [t][d]
  const short* Kh = Kb + ((size_t)(bb * H_ + h) << 10) * D_;    // [t][d]
  const short* Vh = Vtb + (((size_t)(bb * H_ + h) * D_) << 10); // [d][t]
  const int* mrow = mask + bb * T_;
  short* Pw = &sP[w * 16 * PSTRIDE];

  // scale folded with log2(e): exp(s/8) == exp2(s * 0.125*log2e)
  const float SC = 0.125f * 1.44269504088896340736f;

  // Q fragments: A-layout rows tq0+l16, k = ks*32 + quad*8
  bf16x8 aq[2];
#pragma unroll
  for (int ks = 0; ks < 2; ks++)
    aq[ks] = *(const bf16x8*)&Qh[(size_t)(tq0 + l16) * D_ + ks * 32 + quad * 8];

  f32x4 o[4];
  float lsum[4];
#pragma unroll
  for (int nt = 0; nt < 4; nt++)
#pragma unroll
    for (int e = 0; e < 4; e++) o[nt][e] = 0.f;
#pragma unroll
  for (int r = 0; r < 4; r++) lsum[r] = 0.f;

  for (int kt = 0; kt < T_; kt += 128) {
    // S = Q K^T : 16 rows x 128 cols
    f32x4 s[8];
#pragma unroll
    for (int ct = 0; ct < 8; ct++)
#pragma unroll
      for (int e = 0; e < 4; e++) s[ct][e] = 0.f;
#pragma unroll
    for (int ks = 0; ks < 2; ks++)
#pragma unroll
      for (int ct = 0; ct < 8; ct++) {
        bf16x8 bk8 = *(const bf16x8*)&Kh[(size_t)(kt + ct * 16 + l16) * D_ +
                                         ks * 32 + quad * 8];
        s[ct] = __builtin_amdgcn_mfma_f32_16x16x32_bf16(aq[ks], bk8, s[ct], 0, 0, 0);
      }

    float mb[8];
#pragma unroll
    for (int ct = 0; ct < 8; ct++)
      mb[ct] = (mrow[kt + ct * 16 + l16] == 0) ? -1e30f : 0.f;

    // p = exp2(s*SC + mb); accumulate per-lane row partial; stash bf16 P in LDS
#pragma unroll
    for (int ct = 0; ct < 8; ct++)
#pragma unroll
      for (int r = 0; r < 4; r++) {
        float p = __builtin_amdgcn_exp2f(fmaf(s[ct][r], SC, mb[ct]));
        lsum[r] += p;
        Pw[(quad * 4 + r) * PSTRIDE + ct * 16 + l16] = f2bf(p);
      }

    // O += P V   (A = P via LDS in A-layout, B^T = V^T straight from global)
#pragma unroll
    for (int ks2 = 0; ks2 < 4; ks2++) {
      bf16x8 pa = *(const bf16x8*)&Pw[l16 * PSTRIDE + ks2 * 32 + quad * 8];
#pragma unroll
      for (int nt = 0; nt < 4; nt++) {
        bf16x8 bv8 = *(const bf16x8*)&Vh[(((size_t)(nt * 16 + l16)) << 10) +
                                         kt + ks2 * 32 + quad * 8];
        o[nt] = __builtin_amdgcn_mfma_f32_16x16x32_bf16(pa, bv8, o[nt], 0, 0, 0);
      }
    }
  }

  // epilogue: one 16-lane reduction per row, then O/l -> Ob
#pragma unroll
  for (int r = 0; r < 4; r++) {
    float rs = lsum[r];
#pragma unroll
    for (int off = 1; off < 16; off <<= 1) rs += __shfl_xor(rs, off);
    float inv = 1.f / rs;
    int tg = tq0 + quad * 4 + r;
#pragma unroll
    for (int nt = 0; nt < 4; nt++) {
      int col = h * D_ + nt * 16 + l16;
      Ob[(size_t)(bb * T_ + tg) * C_ + col] = f2bf(o[nt][r] * inv);
    }
  }
}

// ---------------- in-place LayerNorm over rows of 1024 ----------------
__global__ __launch_bounds__(256) void k_ln(float* __restrict__ Y,
                                            const float* __restrict__ g,
                                            const float* __restrict__ b) {
  __shared__ float red[4], red2[4];
  const int row = blockIdx.x, tid = threadIdx.x;
  float4* yp = (float4*)(Y + (size_t)row * C_);
  float4 v = yp[tid];
  float sm = v.x + v.y + v.z + v.w;
#pragma unroll
  for (int off = 32; off; off >>= 1) sm += __shfl_xor(sm, off);
  if ((tid & 63) == 0) red[tid >> 6] = sm;
  __syncthreads();
  float mu = (red[0] + red[1] + red[2] + red[3]) * (1.f / C_);
  float dx = v.x - mu, dy = v.y - mu, dz = v.z - mu, dw = v.w - mu;
  float q = dx * dx + dy * dy + dz * dz + dw * dw;
#pragma unroll
  for (int off = 32; off; off >>= 1) q += __shfl_xor(q, off);
  if ((tid & 63) == 0) red2[tid >> 6] = q;
  __syncthreads();
  float var = (red2[0] + red2[1] + red2[2] + red2[3]) * (1.f / C_);
  float rsq = rsqrtf(var + 1e-5f);
  float4 gg = ((const float4*)g)[tid];
  float4 bb = ((const float4*)b)[tid];
  float4 out;
  out.x = dx * rsq * gg.x + bb.x;
  out.y = dy * rsq * gg.y + bb.y;
  out.z = dz * rsq * gg.z + bb.z;
  out.w = dw * rsq * gg.w + bb.w;
  yp[tid] = out;
}

extern "C" void kernel_launch(void* const* d_in, const int* in_sizes, int n_in,
                              void* d_out, int out_size, void* d_ws, size_t ws_size,
                              hipStream_t stream) {
  (void)in_sizes; (void)n_in; (void)out_size; (void)ws_size;
  const float* x    = (const float*)d_in[0];
  const int*   mask = (const int*)d_in[1];
  const float* Wq   = (const float*)d_in[2];
  const float* bq   = (const float*)d_in[3];
  const float* Wk   = (const float*)d_in[4];
  const float* bk   = (const float*)d_in[5];
  const float* Wv   = (const float*)d_in[6];
  const float* bv   = (const float*)d_in[7];
  const float* Wo   = (const float*)d_in[8];
  const float* bo   = (const float*)d_in[9];
  const float* lng  = (const float*)d_in[10];
  const float* lnb  = (const float*)d_in[11];

  char* ws = (char*)d_ws;
  short* xb  = (short*)(ws);                       // 8 MB, reused as Ob after QKV
  short* Wt  = (short*)(ws + ((size_t)8  << 20));  // 8 MB: Wq^T,Wk^T,Wv^T,Wo^T bf16
  short* Qb  = (short*)(ws + ((size_t)16 << 20));  // 8 MB  [B,H,T,D]
  short* Kb  = (short*)(ws + ((size_t)24 << 20));  // 8 MB  [B,H,T,D]
  short* Vtb = (short*)(ws + ((size_t)32 << 20));  // 8 MB  [B,H,D,T]
  short* Ob  = xb;                                 // alias: xb dead after QKV GEMMs
  float* Y   = (float*)d_out;

  k_cast_x<<<dim3(4096), dim3(256), 0, stream>>>(x, xb);
  k_transpose_w<<<dim3(32, 32, 4), dim3(32, 8), 0, stream>>>(Wq, Wk, Wv, Wo, Wt);
  k_qkv<<<dim3(8, 32, 3), dim3(256), 0, stream>>>(xb, Wt, bq, bk, bv, Qb, Kb, Vtb);
  k_attn<<<dim3(16, 16, 4), dim3(256), 0, stream>>>(Qb, Kb, Vtb, mask, Ob);
  k_proj<<<dim3(8, 32), dim3(256), 0, stream>>>(Ob, Wt + (size_t)3 * C_ * C_, bo, Y);
  k_ln<<<dim3(4096), dim3(256), 0, stream>>>(Y, lng, lnb);
}

// Round 3
// 209.291 us; speedup vs baseline: 1.4521x; 1.4332x over previous
//
#include <hip/hip_runtime.h>
#include <stdint.h>

#define B_ 4
#define T_ 1024
#define C_ 1024
#define H_ 16
#define D_ 64
#define M_ 4096   // B_*T_

typedef __attribute__((ext_vector_type(8))) short bf16x8;
typedef __attribute__((ext_vector_type(4))) float f32x4;
typedef __attribute__((ext_vector_type(4))) short short4v;

static __device__ __forceinline__ short f2bf(float f) {
  union { float f; unsigned u; } c; c.f = f;
  unsigned r = (c.u + 0x7fffu + ((c.u >> 16) & 1u)) >> 16;
  return (short)(unsigned short)r;
}

// async global->LDS, 16B per lane. LDS dest is wave-uniform base + lane*16.
static __device__ __forceinline__ void gl2lds16(const void* g, void* l) {
  __builtin_amdgcn_global_load_lds(
      (const __attribute__((address_space(1))) void*)(uintptr_t)g,
      (__attribute__((address_space(3))) void*)(uint32_t)(uintptr_t)l,
      16, 0, 0);
}

// ---------------- cast x -> bf16 ----------------
__global__ __launch_bounds__(256) void k_cast_x(const float* __restrict__ x,
                                                short* __restrict__ xb) {
  int i = blockIdx.x * 256 + threadIdx.x;      // 4 floats per thread
  float4 v = ((const float4*)x)[i];
  short4v o;
  o.x = f2bf(v.x); o.y = f2bf(v.y); o.z = f2bf(v.z); o.w = f2bf(v.w);
  ((short4v*)xb)[i] = o;
}

// ---------------- transpose-cast W[K][N] -> Wt[N][K] bf16 ----------------
__global__ void k_transpose_w(const float* __restrict__ Wq, const float* __restrict__ Wk,
                              const float* __restrict__ Wv, const float* __restrict__ Wo,
                              short* __restrict__ Wt) {
  __shared__ float t[32][33];
  const float* W = (blockIdx.z == 0) ? Wq : (blockIdx.z == 1) ? Wk
                   : (blockIdx.z == 2) ? Wv : Wo;
  short* out = Wt + (size_t)blockIdx.z * C_ * C_;
  int n0 = blockIdx.x * 32, k0 = blockIdx.y * 32;
  int tx = threadIdx.x, ty = threadIdx.y;
#pragma unroll
  for (int i = 0; i < 4; i++)
    t[ty + 8*i][tx] = W[(size_t)(k0 + ty + 8*i) * C_ + n0 + tx];
  __syncthreads();
#pragma unroll
  for (int i = 0; i < 4; i++)
    out[(size_t)(n0 + ty + 8*i) * C_ + k0 + tx] = f2bf(t[tx][ty + 8*i]);
}

// ---------------- shared bt-GEMM body: C[128x128] tile, BK=64 ----------------
static __device__ __forceinline__ void gemm_body(const short* __restrict__ A,
                                                 const short* __restrict__ Bt,
                                                 short* sA, short* sB,
                                                 f32x4 acc[4][4]) {
  const int tid = threadIdx.x;
  const int w = tid >> 6, lane = tid & 63;
  const int quad = lane >> 4, l16 = lane & 15;
  const int m0 = blockIdx.y * 128, n0 = blockIdx.x * 128;
  const int wm = (w >> 1) * 64, wn = (w & 1) * 64;
  const int srow = lane >> 3;          // row within 8-row chunk
  const int sch = lane & 7;            // stored 16B-chunk within row

#pragma unroll
  for (int mt = 0; mt < 4; mt++)
#pragma unroll
    for (int nt = 0; nt < 4; nt++)
#pragma unroll
      for (int e = 0; e < 4; e++) acc[mt][nt][e] = 0.f;

  for (int k0 = 0; k0 < C_; k0 += 64) {
    __syncthreads();
#pragma unroll
    for (int i = 0; i < 4; i++) {
      int c = w * 4 + i;               // 16 chunks of 1KB, 4 per wave
      int row = c * 8 + srow;
      int ch = sch ^ (row & 7);        // XOR swizzle
      gl2lds16(&A[(size_t)(m0 + row) * C_ + k0 + ch * 8], &sA[c * 512]);
      gl2lds16(&Bt[(size_t)(n0 + row) * C_ + k0 + ch * 8], &sB[c * 512]);
    }
    __syncthreads();
#pragma unroll
    for (int ks = 0; ks < 2; ks++) {
      bf16x8 af[4], bfv[4];
      int chq = ks * 4 + quad;
#pragma unroll
      for (int t4 = 0; t4 < 4; t4++) {
        int rowa = wm + t4 * 16 + l16;
        af[t4] = *(const bf16x8*)&sA[rowa * 64 + (chq ^ (rowa & 7)) * 8];
        int rowb = wn + t4 * 16 + l16;
        bfv[t4] = *(const bf16x8*)&sB[rowb * 64 + (chq ^ (rowb & 7)) * 8];
      }
#pragma unroll
      for (int mt = 0; mt < 4; mt++)
#pragma unroll
        for (int nt = 0; nt < 4; nt++)
          acc[mt][nt] = __builtin_amdgcn_mfma_f32_16x16x32_bf16(
              af[mt], bfv[nt], acc[mt][nt], 0, 0, 0);
    }
  }
}

// ---------------- QKV projection (z = 0:Q, 1:K, 2:V-transposed) ----------------
// mode 2 transposes its C-tile through LDS and writes V^T [B,H,D,T] with
// contiguous 256B runs (no 2B scatter at 2KB stride).
__global__ __launch_bounds__(256) void k_qkv(
    const short* __restrict__ A, const short* __restrict__ WtAll,
    const float* __restrict__ bq, const float* __restrict__ bk,
    const float* __restrict__ bv,
    short* __restrict__ Qb, short* __restrict__ Kb, short* __restrict__ Vtb) {
  __shared__ short sU[17408];          // gemm: sA=sU[0:8192], sB=sU[8192:16384]
  const int mode = blockIdx.z;
  const short* Bt = WtAll + (size_t)mode * C_ * C_;
  const float* bias = (mode == 0) ? bq : (mode == 1) ? bk : bv;
  f32x4 acc[4][4];
  gemm_body(A, Bt, sU, sU + 8192, acc);

  const int tid = threadIdx.x;
  const int w = tid >> 6, lane = tid & 63;
  const int quad = lane >> 4, l16 = lane & 15;
  const int m0 = blockIdx.y * 128, n0 = blockIdx.x * 128;
  const int wm = (w >> 1) * 64, wn = (w & 1) * 64;

  if (mode < 2) {
#pragma unroll
    for (int mt = 0; mt < 4; mt++) {
#pragma unroll
      for (int nt = 0; nt < 4; nt++) {
        int ng = n0 + wn + nt * 16 + l16;
        float bval = bias[ng];
        int h = ng >> 6, d = ng & 63;
#pragma unroll
        for (int r = 0; r < 4; r++) {
          int mg = m0 + wm + mt * 16 + quad * 4 + r;
          int bb = mg >> 10, t = mg & 1023;
          short v16 = f2bf(acc[mt][nt][r] + bval);
          if (mode == 0)
            Qb[(((size_t)(bb * H_ + h) << 10) + t) * D_ + d] = v16;
          else
            Kb[(((size_t)(bb * H_ + h) << 10) + t) * D_ + d] = v16;
        }
      }
    }
  } else {
    __syncthreads();   // all waves done with gemm LDS reads
    // transposed bf16 tile: sU[n_local][m_local], stride 136 (pad 8)
#pragma unroll
    for (int nt = 0; nt < 4; nt++) {
      int nl = wn + nt * 16 + l16;
      float bval = bias[n0 + nl];
#pragma unroll
      for (int mt = 0; mt < 4; mt++)
#pragma unroll
        for (int r = 0; r < 4; r++)
          sU[nl * 136 + wm + mt * 16 + quad * 4 + r] = f2bf(acc[mt][nt][r] + bval);
    }
    __syncthreads();
    // copy out: thread -> half row (8 int4 = 128B contiguous along t)
    int dr = tid >> 1;
    int dg = n0 + dr, hd = dg >> 6, dl = dg & 63;
    int bb2 = m0 >> 10, t0 = m0 & 1023;
    size_t base = (((size_t)(bb2 * H_ + hd) * D_ + dl) << 10) + t0;
#pragma unroll
    for (int i = 0; i < 8; i++) {
      int jj = (tid & 1) * 8 + i;
      *(int4*)&Vtb[base + jj * 8] = *(const int4*)&sU[dr * 136 + jj * 8];
    }
  }
}

// ---------------- output projection, fp32 out ----------------
__global__ __launch_bounds__(256) void k_proj(
    const short* __restrict__ A, const short* __restrict__ Bt,
    const float* __restrict__ bias, float* __restrict__ Y) {
  __shared__ short sA[8192];
  __shared__ short sB[8192];
  f32x4 acc[4][4];
  gemm_body(A, Bt, sA, sB, acc);

  const int tid = threadIdx.x;
  const int w = tid >> 6, lane = tid & 63;
  const int quad = lane >> 4, l16 = lane & 15;
  const int m0 = blockIdx.y * 128, n0 = blockIdx.x * 128;
  const int wm = (w >> 1) * 64, wn = (w & 1) * 64;

#pragma unroll
  for (int mt = 0; mt < 4; mt++)
#pragma unroll
    for (int nt = 0; nt < 4; nt++) {
      int ng = n0 + wn + nt * 16 + l16;
      float bval = bias[ng];
#pragma unroll
      for (int r = 0; r < 4; r++) {
        int mg = m0 + wm + mt * 16 + quad * 4 + r;
        Y[(size_t)mg * C_ + ng] = acc[mt][nt][r] + bval;
      }
    }
}

// ---------------- flash attention, LDS-staged, XCD-swizzled ----------------
// block = 128 q-rows x one (b,h); 4 waves x 32 rows; KV-tile = 128.
// K/V staged to LDS via global_load_lds (XOR swizzle), mask bias staged once.
// Fixed-shift softmax, deferred row-sum, P per-wave LDS round-trip.
#define PSTRIDE 136
__global__ __launch_bounds__(256, 2) void k_attn(
    const short* __restrict__ Qb, const short* __restrict__ Kb,
    const short* __restrict__ Vtb, const int* __restrict__ mask,
    short* __restrict__ Ob) {
  __shared__ short sK[8192];           // 128 x 64, 8 chunks/row, swizzled
  __shared__ short sV[8192];           // 64 x 128, 16 chunks/row, swizzled
  __shared__ short sP[4 * 32 * PSTRIDE];
  __shared__ float sBias[1024];
  const int tid = threadIdx.x;
  const int w = tid >> 6, lane = tid & 63;
  const int quad = lane >> 4, l16 = lane & 15;

  // XCD swizzle: all 8 q-blocks of a (b,h) land on the same XCD (bx % 8 fixed)
  const int bx = blockIdx.x;
  const int xcd = bx & 7, j = bx >> 3;
  const int qb = j & 7, u = j >> 3;
  const int h = xcd * 2 + (u & 1), bb = u >> 1;
  const int tq0 = qb * 128 + w * 32;

  const short* Qh = Qb + ((size_t)(bb * H_ + h) << 10) * D_;    // [t][d]
  const short* Kh = Kb + ((size_t)(bb * H_ + h) << 10) * D_;    // [t][d]
  const short* Vh = Vtb + (((size_t)(bb * H_ + h) * D_) << 10); // [d][t]
  const int* mrow = mask + bb * T_;
  short* Pw = &sP[w * 32 * PSTRIDE];

  const float SC = 0.125f * 1.44269504088896340736f;  // 1/sqrt(D) * log2(e)

  // stage mask bias once (visible after first loop barrier)
  {
    int4 m4 = ((const int4*)mrow)[tid];
    float4 bv4;
    bv4.x = m4.x ? 0.f : -1e30f; bv4.y = m4.y ? 0.f : -1e30f;
    bv4.z = m4.z ? 0.f : -1e30f; bv4.w = m4.w ? 0.f : -1e30f;
    ((float4*)sBias)[tid] = bv4;
  }

  // Q fragments: A-layout rows tq0 + rt*16 + l16, k = ks*32 + quad*8
  bf16x8 aq[2][2];
#pragma unroll
  for (int rt = 0; rt < 2; rt++)
#pragma unroll
    for (int ks = 0; ks < 2; ks++)
      aq[rt][ks] = *(const bf16x8*)&Qh[(size_t)(tq0 + rt * 16 + l16) * D_ +
                                       ks * 32 + quad * 8];

  f32x4 o[2][4];
  float lsum[2][4];
#pragma unroll
  for (int rt = 0; rt < 2; rt++) {
#pragma unroll
    for (int nt = 0; nt < 4; nt++)
#pragma unroll
      for (int e = 0; e < 4; e++) o[rt][nt][e] = 0.f;
#pragma unroll
    for (int r = 0; r < 4; r++) lsum[rt][r] = 0.f;
  }

  for (int kt = 0; kt < T_; kt += 128) {
    __syncthreads();   // previous tile fully consumed
    // stage K tile: 16 x 1KB chunks, wave w does 4; 8 rows/chunk, 8 16B-chunks/row
#pragma unroll
    for (int i2 = 0; i2 < 4; i2++) {
      int i = w * 4 + i2;
      int row = i * 8 + (lane >> 3);
      int g = (lane & 7) ^ (row & 7);
      gl2lds16(&Kh[(size_t)(kt + row) * D_ + g * 8], &sK[i * 512]);
    }
    // stage V^T tile: 16 x 1KB chunks; 4 rows/chunk, 16 16B-chunks/row
#pragma unroll
    for (int i2 = 0; i2 < 4; i2++) {
      int i = w * 4 + i2;
      int row = i * 4 + (lane >> 4);
      int g = (lane & 15) ^ (row & 15);
      gl2lds16(&Vh[((size_t)row << 10) + kt + g * 8], &sV[i * 512]);
    }
    __syncthreads();   // staged data visible (barrier drains vmcnt)

    // S = Q K^T : 32 rows x 128 cols per wave
    f32x4 s[2][8];
#pragma unroll
    for (int rt = 0; rt < 2; rt++)
#pragma unroll
      for (int ct = 0; ct < 8; ct++)
#pragma unroll
        for (int e = 0; e < 4; e++) s[rt][ct][e] = 0.f;

#pragma unroll
    for (int ks = 0; ks < 2; ks++)
#pragma unroll
      for (int ct = 0; ct < 8; ct++) {
        int rowb = ct * 16 + l16;
        bf16x8 bk8 = *(const bf16x8*)&sK[rowb * 64 +
                                         (((ks * 4 + quad) ^ (rowb & 7)) * 8)];
        s[0][ct] = __builtin_amdgcn_mfma_f32_16x16x32_bf16(aq[0][ks], bk8, s[0][ct], 0, 0, 0);
        s[1][ct] = __builtin_amdgcn_mfma_f32_16x16x32_bf16(aq[1][ks], bk8, s[1][ct], 0, 0, 0);
      }

    float mb[8];
#pragma unroll
    for (int ct = 0; ct < 8; ct++) mb[ct] = sBias[kt + ct * 16 + l16];

    // p = exp2(s*SC + mb); per-lane row partials; bf16 P into per-wave LDS
#pragma unroll
    for (int rt = 0; rt < 2; rt++)
#pragma unroll
      for (int ct = 0; ct < 8; ct++)
#pragma unroll
        for (int r = 0; r < 4; r++) {
          float p = __builtin_amdgcn_exp2f(fmaf(s[rt][ct][r], SC, mb[ct]));
          lsum[rt][r] += p;
          Pw[(rt * 16 + quad * 4 + r) * PSTRIDE + ct * 16 + l16] = f2bf(p);
        }

    // O += P V
#pragma unroll
    for (int ks2 = 0; ks2 < 4; ks2++) {
      bf16x8 pa0 = *(const bf16x8*)&Pw[l16 * PSTRIDE + ks2 * 32 + quad * 8];
      bf16x8 pa1 = *(const bf16x8*)&Pw[(16 + l16) * PSTRIDE + ks2 * 32 + quad * 8];
#pragma unroll
      for (int nt = 0; nt < 4; nt++) {
        int rowv = nt * 16 + l16;
        bf16x8 bv8 = *(const bf16x8*)&sV[rowv * 128 +
                                         (((ks2 * 4 + quad) ^ (rowv & 15)) * 8)];
        o[0][nt] = __builtin_amdgcn_mfma_f32_16x16x32_bf16(pa0, bv8, o[0][nt], 0, 0, 0);
        o[1][nt] = __builtin_amdgcn_mfma_f32_16x16x32_bf16(pa1, bv8, o[1][nt], 0, 0, 0);
      }
    }
  }

  // epilogue: 16-lane reduction per row, then O/l -> Ob
#pragma unroll
  for (int rt = 0; rt < 2; rt++)
#pragma unroll
    for (int r = 0; r < 4; r++) {
      float rs = lsum[rt][r];
#pragma unroll
      for (int off = 1; off < 16; off <<= 1) rs += __shfl_xor(rs, off);
      float inv = 1.f / rs;
      int tg = tq0 + rt * 16 + quad * 4 + r;
#pragma unroll
      for (int nt = 0; nt < 4; nt++) {
        int col = h * D_ + nt * 16 + l16;
        Ob[(size_t)(bb * T_ + tg) * C_ + col] = f2bf(o[rt][nt][r] * inv);
      }
    }
}

// ---------------- in-place LayerNorm over rows of 1024 ----------------
__global__ __launch_bounds__(256) void k_ln(float* __restrict__ Y,
                                            const float* __restrict__ g,
                                            const float* __restrict__ b) {
  __shared__ float red[4], red2[4];
  const int row = blockIdx.x, tid = threadIdx.x;
  float4* yp = (float4*)(Y + (size_t)row * C_);
  float4 v = yp[tid];
  float sm = v.x + v.y + v.z + v.w;
#pragma unroll
  for (int off = 32; off; off >>= 1) sm += __shfl_xor(sm, off);
  if ((tid & 63) == 0) red[tid >> 6] = sm;
  __syncthreads();
  float mu = (red[0] + red[1] + red[2] + red[3]) * (1.f / C_);
  float dx = v.x - mu, dy = v.y - mu, dz = v.z - mu, dw = v.w - mu;
  float q = dx * dx + dy * dy + dz * dz + dw * dw;
#pragma unroll
  for (int off = 32; off; off >>= 1) q += __shfl_xor(q, off);
  if ((tid & 63) == 0) red2[tid >> 6] = q;
  __syncthreads();
  float var = (red2[0] + red2[1] + red2[2] + red2[3]) * (1.f / C_);
  float rsq = rsqrtf(var + 1e-5f);
  float4 gg = ((const float4*)g)[tid];
  float4 bb = ((const float4*)b)[tid];
  float4 out;
  out.x = dx * rsq * gg.x + bb.x;
  out.y = dy * rsq * gg.y + bb.y;
  out.z = dz * rsq * gg.z + bb.z;
  out.w = dw * rsq * gg.w + bb.w;
  yp[tid] = out;
}

extern "C" void kernel_launch(void* const* d_in, const int* in_sizes, int n_in,
                              void* d_out, int out_size, void* d_ws, size_t ws_size,
                              hipStream_t stream) {
  (void)in_sizes; (void)n_in; (void)out_size; (void)ws_size;
  const float* x    = (const float*)d_in[0];
  const int*   mask = (const int*)d_in[1];
  const float* Wq   = (const float*)d_in[2];
  const float* bq   = (const float*)d_in[3];
  const float* Wk   = (const float*)d_in[4];
  const float* bk   = (const float*)d_in[5];
  const float* Wv   = (const float*)d_in[6];
  const float* bv   = (const float*)d_in[7];
  const float* Wo   = (const float*)d_in[8];
  const float* bo   = (const float*)d_in[9];
  const float* lng  = (const float*)d_in[10];
  const float* lnb  = (const float*)d_in[11];

  char* ws = (char*)d_ws;
  short* xb  = (short*)(ws);                       // 8 MB, reused as Ob after QKV
  short* Wt  = (short*)(ws + ((size_t)8  << 20));  // 8 MB: Wq^T,Wk^T,Wv^T,Wo^T bf16
  short* Qb  = (short*)(ws + ((size_t)16 << 20));  // 8 MB  [B,H,T,D]
  short* Kb  = (short*)(ws + ((size_t)24 << 20));  // 8 MB  [B,H,T,D]
  short* Vtb = (short*)(ws + ((size_t)32 << 20));  // 8 MB  [B,H,D,T]
  short* Ob  = xb;                                 // alias: xb dead after QKV GEMMs
  float* Y   = (float*)d_out;

  k_cast_x<<<dim3(4096), dim3(256), 0, stream>>>(x, xb);
  k_transpose_w<<<dim3(32, 32, 4), dim3(32, 8), 0, stream>>>(Wq, Wk, Wv, Wo, Wt);
  k_qkv<<<dim3(8, 32, 3), dim3(256), 0, stream>>>(xb, Wt, bq, bk, bv, Qb, Kb, Vtb);
  k_attn<<<dim3(512), dim3(256), 0, stream>>>(Qb, Kb, Vtb, mask, Ob);
  k_proj<<<dim3(8, 32), dim3(256), 0, stream>>>(Ob, Wt + (size_t)3 * C_ * C_, bo, Y);
  k_ln<<<dim3(4096), dim3(256), 0, stream>>>(Y, lng, lnb);
}

// Round 4
// 199.521 us; speedup vs baseline: 1.5232x; 1.0490x over previous
//
#include <hip/hip_runtime.h>
#include <stdint.h>

#define B_ 4
#define T_ 1024
#define C_ 1024
#define H_ 16
#define D_ 64
#define M_ 4096   // B_*T_

typedef __attribute__((ext_vector_type(8))) short bf16x8;
typedef __attribute__((ext_vector_type(4))) float f32x4;
typedef __attribute__((ext_vector_type(4))) short short4v;

static __device__ __forceinline__ short f2bf(float f) {
  union { float f; unsigned u; } c; c.f = f;
  unsigned r = (c.u + 0x7fffu + ((c.u >> 16) & 1u)) >> 16;
  return (short)(unsigned short)r;
}

// async global->LDS, 16B per lane. LDS dest is wave-uniform base + lane*16.
static __device__ __forceinline__ void gl2lds16(const void* g, void* l) {
  __builtin_amdgcn_global_load_lds(
      (const __attribute__((address_space(1))) void*)(uintptr_t)g,
      (__attribute__((address_space(3))) void*)(uint32_t)(uintptr_t)l,
      16, 0, 0);
}

// ---------------- fused: cast x -> bf16  +  transpose-cast W -> Wt ----------------
// blocks [0,4096): cast; blocks [4096,8192): W transpose (32x32 tile each).
__global__ __launch_bounds__(256) void k_prep(
    const float* __restrict__ x, short* __restrict__ xb,
    const float* __restrict__ Wq, const float* __restrict__ Wk,
    const float* __restrict__ Wv, const float* __restrict__ Wo,
    short* __restrict__ Wt) {
  __shared__ float t[32][33];
  const int id = blockIdx.x, tid = threadIdx.x;
  if (id < 4096) {
    int i = id * 256 + tid;
    float4 v = ((const float4*)x)[i];
    short4v o;
    o.x = f2bf(v.x); o.y = f2bf(v.y); o.z = f2bf(v.z); o.w = f2bf(v.w);
    ((short4v*)xb)[i] = o;
    return;
  }
  int j = id - 4096;
  int bz = j >> 10, r = j & 1023;
  int by = r >> 5, bx = r & 31;
  const float* W = (bz == 0) ? Wq : (bz == 1) ? Wk : (bz == 2) ? Wv : Wo;
  short* out = Wt + (size_t)bz * C_ * C_;
  int n0 = bx * 32, k0 = by * 32;
  int tx = tid & 31, ty = tid >> 5;
#pragma unroll
  for (int i = 0; i < 4; i++)
    t[ty + 8*i][tx] = W[(size_t)(k0 + ty + 8*i) * C_ + n0 + tx];
  __syncthreads();
#pragma unroll
  for (int i = 0; i < 4; i++)
    out[(size_t)(n0 + ty + 8*i) * C_ + k0 + tx] = f2bf(t[tx][ty + 8*i]);
}

// ---------------- bt-GEMM body: C[128x128] tile, BK=64, XOR-swizzled LDS ----------------
static __device__ __forceinline__ void gemm_body(const short* __restrict__ A,
                                                 const short* __restrict__ Bt,
                                                 short* sA, short* sB,
                                                 f32x4 acc[4][4], int m0, int n0) {
  const int tid = threadIdx.x;
  const int w = tid >> 6, lane = tid & 63;
  const int quad = lane >> 4, l16 = lane & 15;
  const int wm = (w >> 1) * 64, wn = (w & 1) * 64;
  const int srow = lane >> 3;          // row within 8-row chunk
  const int sch = lane & 7;            // stored 16B-chunk within row

#pragma unroll
  for (int mt = 0; mt < 4; mt++)
#pragma unroll
    for (int nt = 0; nt < 4; nt++)
#pragma unroll
      for (int e = 0; e < 4; e++) acc[mt][nt][e] = 0.f;

  for (int k0 = 0; k0 < C_; k0 += 64) {
    __syncthreads();
#pragma unroll
    for (int i = 0; i < 4; i++) {
      int c = w * 4 + i;               // 16 chunks of 1KB, 4 per wave
      int row = c * 8 + srow;
      int ch = sch ^ (row & 7);        // XOR swizzle
      gl2lds16(&A[(size_t)(m0 + row) * C_ + k0 + ch * 8], &sA[c * 512]);
      gl2lds16(&Bt[(size_t)(n0 + row) * C_ + k0 + ch * 8], &sB[c * 512]);
    }
    __syncthreads();
#pragma unroll
    for (int ks = 0; ks < 2; ks++) {
      bf16x8 af[4], bfv[4];
      int chq = ks * 4 + quad;
#pragma unroll
      for (int t4 = 0; t4 < 4; t4++) {
        int rowa = wm + t4 * 16 + l16;
        af[t4] = *(const bf16x8*)&sA[rowa * 64 + (chq ^ (rowa & 7)) * 8];
        int rowb = wn + t4 * 16 + l16;
        bfv[t4] = *(const bf16x8*)&sB[rowb * 64 + (chq ^ (rowb & 7)) * 8];
      }
#pragma unroll
      for (int mt = 0; mt < 4; mt++)
#pragma unroll
        for (int nt = 0; nt < 4; nt++)
          acc[mt][nt] = __builtin_amdgcn_mfma_f32_16x16x32_bf16(
              af[mt], bfv[nt], acc[mt][nt], 0, 0, 0);
    }
  }
}

// ---------------- QKV projection, mode-fastest 1-D grid ----------------
// id = z + 3*bx + 24*by -> 3 co-resident blocks/CU span all modes and share A-tile.
__global__ __launch_bounds__(256) void k_qkv(
    const short* __restrict__ A, const short* __restrict__ WtAll,
    const float* __restrict__ bq, const float* __restrict__ bk,
    const float* __restrict__ bv,
    short* __restrict__ Qb, short* __restrict__ Kb, short* __restrict__ Vtb) {
  __shared__ short sU[17408];          // gemm: sA=sU[0:8192], sB=sU[8192:16384]
  const int id = blockIdx.x;
  const int mode = id % 3;
  const int j = id / 3;
  const int bx = j & 7, by = j >> 3;
  const int m0 = by * 128, n0 = bx * 128;
  const short* Bt = WtAll + (size_t)mode * C_ * C_;
  const float* bias = (mode == 0) ? bq : (mode == 1) ? bk : bv;
  f32x4 acc[4][4];
  gemm_body(A, Bt, sU, sU + 8192, acc, m0, n0);

  const int tid = threadIdx.x;
  const int w = tid >> 6, lane = tid & 63;
  const int quad = lane >> 4, l16 = lane & 15;
  const int wm = (w >> 1) * 64, wn = (w & 1) * 64;

  if (mode < 2) {
#pragma unroll
    for (int mt = 0; mt < 4; mt++) {
#pragma unroll
      for (int nt = 0; nt < 4; nt++) {
        int ng = n0 + wn + nt * 16 + l16;
        float bval = bias[ng];
        int h = ng >> 6, d = ng & 63;
#pragma unroll
        for (int r = 0; r < 4; r++) {
          int mg = m0 + wm + mt * 16 + quad * 4 + r;
          int bb = mg >> 10, t = mg & 1023;
          short v16 = f2bf(acc[mt][nt][r] + bval);
          if (mode == 0)
            Qb[(((size_t)(bb * H_ + h) << 10) + t) * D_ + d] = v16;
          else
            Kb[(((size_t)(bb * H_ + h) << 10) + t) * D_ + d] = v16;
        }
      }
    }
  } else {
    __syncthreads();   // all waves done with gemm LDS reads
    // transposed bf16 tile: sU[n_local][m_local], stride 136 (pad 8)
#pragma unroll
    for (int nt = 0; nt < 4; nt++) {
      int nl = wn + nt * 16 + l16;
      float bval = bias[n0 + nl];
#pragma unroll
      for (int mt = 0; mt < 4; mt++)
#pragma unroll
        for (int r = 0; r < 4; r++)
          sU[nl * 136 + wm + mt * 16 + quad * 4 + r] = f2bf(acc[mt][nt][r] + bval);
    }
    __syncthreads();
    // copy out: thread -> half row (8 int4 = 128B contiguous along t)
    int dr = tid >> 1;
    int dg = n0 + dr, hd = dg >> 6, dl = dg & 63;
    int bb2 = m0 >> 10, t0 = m0 & 1023;
    size_t base = (((size_t)(bb2 * H_ + hd) * D_ + dl) << 10) + t0;
#pragma unroll
    for (int i = 0; i < 8; i++) {
      int jj = (tid & 1) * 8 + i;
      *(int4*)&Vtb[base + jj * 8] = *(const int4*)&sU[dr * 136 + jj * 8];
    }
  }
}

// ---------------- output projection: 64x128 tiles for 2 blocks/CU ----------------
__global__ __launch_bounds__(256) void k_proj(
    const short* __restrict__ A, const short* __restrict__ Bt,
    const float* __restrict__ bias, float* __restrict__ Y) {
  __shared__ short sA[4096];           // 64 x 64
  __shared__ short sB[8192];           // 128 x 64
  const int tid = threadIdx.x;
  const int w = tid >> 6, lane = tid & 63;
  const int quad = lane >> 4, l16 = lane & 15;
  const int m0 = blockIdx.y * 64, n0 = blockIdx.x * 128;
  const int wm = (w >> 1) * 32, wn = (w & 1) * 64;
  const int srow = lane >> 3, sch = lane & 7;

  f32x4 acc[2][4];
#pragma unroll
  for (int mt = 0; mt < 2; mt++)
#pragma unroll
    for (int nt = 0; nt < 4; nt++)
#pragma unroll
      for (int e = 0; e < 4; e++) acc[mt][nt][e] = 0.f;

  for (int k0 = 0; k0 < C_; k0 += 64) {
    __syncthreads();
#pragma unroll
    for (int i = 0; i < 6; i++) {      // 24 chunks of 1KB (8 A + 16 B), 6 per wave
      int c = w * 6 + i;
      if (c < 8) {
        int row = c * 8 + srow;
        int ch = sch ^ (row & 7);
        gl2lds16(&A[(size_t)(m0 + row) * C_ + k0 + ch * 8], &sA[c * 512]);
      } else {
        int c2 = c - 8;
        int row = c2 * 8 + srow;
        int ch = sch ^ (row & 7);
        gl2lds16(&Bt[(size_t)(n0 + row) * C_ + k0 + ch * 8], &sB[c2 * 512]);
      }
    }
    __syncthreads();
#pragma unroll
    for (int ks = 0; ks < 2; ks++) {
      bf16x8 af[2], bfv[4];
      int chq = ks * 4 + quad;
#pragma unroll
      for (int t2 = 0; t2 < 2; t2++) {
        int rowa = wm + t2 * 16 + l16;
        af[t2] = *(const bf16x8*)&sA[rowa * 64 + (chq ^ (rowa & 7)) * 8];
      }
#pragma unroll
      for (int t4 = 0; t4 < 4; t4++) {
        int rowb = wn + t4 * 16 + l16;
        bfv[t4] = *(const bf16x8*)&sB[rowb * 64 + (chq ^ (rowb & 7)) * 8];
      }
#pragma unroll
      for (int mt = 0; mt < 2; mt++)
#pragma unroll
        for (int nt = 0; nt < 4; nt++)
          acc[mt][nt] = __builtin_amdgcn_mfma_f32_16x16x32_bf16(
              af[mt], bfv[nt], acc[mt][nt], 0, 0, 0);
    }
  }

#pragma unroll
  for (int mt = 0; mt < 2; mt++)
#pragma unroll
    for (int nt = 0; nt < 4; nt++) {
      int ng = n0 + wn + nt * 16 + l16;
      float bval = bias[ng];
#pragma unroll
      for (int r = 0; r < 4; r++) {
        int mg = m0 + wm + mt * 16 + quad * 4 + r;
        Y[(size_t)mg * C_ + ng] = acc[mt][nt][r] + bval;
      }
    }
}

// ---------------- flash attention, LDS-staged, XCD-swizzled ----------------
#define PSTRIDE 136
__global__ __launch_bounds__(256, 2) void k_attn(
    const short* __restrict__ Qb, const short* __restrict__ Kb,
    const short* __restrict__ Vtb, const int* __restrict__ mask,
    short* __restrict__ Ob) {
  __shared__ short sK[8192];           // 128 x 64, swizzled
  __shared__ short sV[8192];           // 64 x 128, swizzled
  __shared__ short sP[4 * 32 * PSTRIDE];
  __shared__ float sBias[1024];
  const int tid = threadIdx.x;
  const int w = tid >> 6, lane = tid & 63;
  const int quad = lane >> 4, l16 = lane & 15;

  const int bx = blockIdx.x;
  const int xcd = bx & 7, j = bx >> 3;
  const int qb = j & 7, u = j >> 3;
  const int h = xcd * 2 + (u & 1), bb = u >> 1;
  const int tq0 = qb * 128 + w * 32;

  const short* Qh = Qb + ((size_t)(bb * H_ + h) << 10) * D_;    // [t][d]
  const short* Kh = Kb + ((size_t)(bb * H_ + h) << 10) * D_;    // [t][d]
  const short* Vh = Vtb + (((size_t)(bb * H_ + h) * D_) << 10); // [d][t]
  const int* mrow = mask + bb * T_;
  short* Pw = &sP[w * 32 * PSTRIDE];

  const float SC = 0.125f * 1.44269504088896340736f;  // 1/sqrt(D) * log2(e)

  {
    int4 m4 = ((const int4*)mrow)[tid];
    float4 bv4;
    bv4.x = m4.x ? 0.f : -1e30f; bv4.y = m4.y ? 0.f : -1e30f;
    bv4.z = m4.z ? 0.f : -1e30f; bv4.w = m4.w ? 0.f : -1e30f;
    ((float4*)sBias)[tid] = bv4;
  }

  bf16x8 aq[2][2];
#pragma unroll
  for (int rt = 0; rt < 2; rt++)
#pragma unroll
    for (int ks = 0; ks < 2; ks++)
      aq[rt][ks] = *(const bf16x8*)&Qh[(size_t)(tq0 + rt * 16 + l16) * D_ +
                                       ks * 32 + quad * 8];

  f32x4 o[2][4];
  float lsum[2][4];
#pragma unroll
  for (int rt = 0; rt < 2; rt++) {
#pragma unroll
    for (int nt = 0; nt < 4; nt++)
#pragma unroll
      for (int e = 0; e < 4; e++) o[rt][nt][e] = 0.f;
#pragma unroll
    for (int r = 0; r < 4; r++) lsum[rt][r] = 0.f;
  }

  for (int kt = 0; kt < T_; kt += 128) {
    __syncthreads();
#pragma unroll
    for (int i2 = 0; i2 < 4; i2++) {
      int i = w * 4 + i2;
      int row = i * 8 + (lane >> 3);
      int g = (lane & 7) ^ (row & 7);
      gl2lds16(&Kh[(size_t)(kt + row) * D_ + g * 8], &sK[i * 512]);
    }
#pragma unroll
    for (int i2 = 0; i2 < 4; i2++) {
      int i = w * 4 + i2;
      int row = i * 4 + (lane >> 4);
      int g = (lane & 15) ^ (row & 15);
      gl2lds16(&Vh[((size_t)row << 10) + kt + g * 8], &sV[i * 512]);
    }
    __syncthreads();

    f32x4 s[2][8];
#pragma unroll
    for (int rt = 0; rt < 2; rt++)
#pragma unroll
      for (int ct = 0; ct < 8; ct++)
#pragma unroll
        for (int e = 0; e < 4; e++) s[rt][ct][e] = 0.f;

#pragma unroll
    for (int ks = 0; ks < 2; ks++)
#pragma unroll
      for (int ct = 0; ct < 8; ct++) {
        int rowb = ct * 16 + l16;
        bf16x8 bk8 = *(const bf16x8*)&sK[rowb * 64 +
                                         (((ks * 4 + quad) ^ (rowb & 7)) * 8)];
        s[0][ct] = __builtin_amdgcn_mfma_f32_16x16x32_bf16(aq[0][ks], bk8, s[0][ct], 0, 0, 0);
        s[1][ct] = __builtin_amdgcn_mfma_f32_16x16x32_bf16(aq[1][ks], bk8, s[1][ct], 0, 0, 0);
      }

    float mb[8];
#pragma unroll
    for (int ct = 0; ct < 8; ct++) mb[ct] = sBias[kt + ct * 16 + l16];

#pragma unroll
    for (int rt = 0; rt < 2; rt++)
#pragma unroll
      for (int ct = 0; ct < 8; ct++)
#pragma unroll
        for (int r = 0; r < 4; r++) {
          float p = __builtin_amdgcn_exp2f(fmaf(s[rt][ct][r], SC, mb[ct]));
          lsum[rt][r] += p;
          Pw[(rt * 16 + quad * 4 + r) * PSTRIDE + ct * 16 + l16] = f2bf(p);
        }

#pragma unroll
    for (int ks2 = 0; ks2 < 4; ks2++) {
      bf16x8 pa0 = *(const bf16x8*)&Pw[l16 * PSTRIDE + ks2 * 32 + quad * 8];
      bf16x8 pa1 = *(const bf16x8*)&Pw[(16 + l16) * PSTRIDE + ks2 * 32 + quad * 8];
#pragma unroll
      for (int nt = 0; nt < 4; nt++) {
        int rowv = nt * 16 + l16;
        bf16x8 bv8 = *(const bf16x8*)&sV[rowv * 128 +
                                         (((ks2 * 4 + quad) ^ (rowv & 15)) * 8)];
        o[0][nt] = __builtin_amdgcn_mfma_f32_16x16x32_bf16(pa0, bv8, o[0][nt], 0, 0, 0);
        o[1][nt] = __builtin_amdgcn_mfma_f32_16x16x32_bf16(pa1, bv8, o[1][nt], 0, 0, 0);
      }
    }
  }

#pragma unroll
  for (int rt = 0; rt < 2; rt++)
#pragma unroll
    for (int r = 0; r < 4; r++) {
      float rs = lsum[rt][r];
#pragma unroll
      for (int off = 1; off < 16; off <<= 1) rs += __shfl_xor(rs, off);
      float inv = 1.f / rs;
      int tg = tq0 + rt * 16 + quad * 4 + r;
#pragma unroll
      for (int nt = 0; nt < 4; nt++) {
        int col = h * D_ + nt * 16 + l16;
        Ob[(size_t)(bb * T_ + tg) * C_ + col] = f2bf(o[rt][nt][r] * inv);
      }
    }
}

// ---------------- in-place LayerNorm over rows of 1024 ----------------
__global__ __launch_bounds__(256) void k_ln(float* __restrict__ Y,
                                            const float* __restrict__ g,
                                            const float* __restrict__ b) {
  __shared__ float red[4], red2[4];
  const int row = blockIdx.x, tid = threadIdx.x;
  float4* yp = (float4*)(Y + (size_t)row * C_);
  float4 v = yp[tid];
  float sm = v.x + v.y + v.z + v.w;
#pragma unroll
  for (int off = 32; off; off >>= 1) sm += __shfl_xor(sm, off);
  if ((tid & 63) == 0) red[tid >> 6] = sm;
  __syncthreads();
  float mu = (red[0] + red[1] + red[2] + red[3]) * (1.f / C_);
  float dx = v.x - mu, dy = v.y - mu, dz = v.z - mu, dw = v.w - mu;
  float q = dx * dx + dy * dy + dz * dz + dw * dw;
#pragma unroll
  for (int off = 32; off; off >>= 1) q += __shfl_xor(q, off);
  if ((tid & 63) == 0) red2[tid >> 6] = q;
  __syncthreads();
  float var = (red2[0] + red2[1] + red2[2] + red2[3]) * (1.f / C_);
  float rsq = rsqrtf(var + 1e-5f);
  float4 gg = ((const float4*)g)[tid];
  float4 bb = ((const float4*)b)[tid];
  float4 out;
  out.x = dx * rsq * gg.x + bb.x;
  out.y = dy * rsq * gg.y + bb.y;
  out.z = dz * rsq * gg.z + bb.z;
  out.w = dw * rsq * gg.w + bb.w;
  yp[tid] = out;
}

extern "C" void kernel_launch(void* const* d_in, const int* in_sizes, int n_in,
                              void* d_out, int out_size, void* d_ws, size_t ws_size,
                              hipStream_t stream) {
  (void)in_sizes; (void)n_in; (void)out_size; (void)ws_size;
  const float* x    = (const float*)d_in[0];
  const int*   mask = (const int*)d_in[1];
  const float* Wq   = (const float*)d_in[2];
  const float* bq   = (const float*)d_in[3];
  const float* Wk   = (const float*)d_in[4];
  const float* bk   = (const float*)d_in[5];
  const float* Wv   = (const float*)d_in[6];
  const float* bv   = (const float*)d_in[7];
  const float* Wo   = (const float*)d_in[8];
  const float* bo   = (const float*)d_in[9];
  const float* lng  = (const float*)d_in[10];
  const float* lnb  = (const float*)d_in[11];

  char* ws = (char*)d_ws;
  short* xb  = (short*)(ws);                       // 8 MB, reused as Ob after QKV
  short* Wt  = (short*)(ws + ((size_t)8  << 20));  // 8 MB: Wq^T,Wk^T,Wv^T,Wo^T bf16
  short* Qb  = (short*)(ws + ((size_t)16 << 20));  // 8 MB  [B,H,T,D]
  short* Kb  = (short*)(ws + ((size_t)24 << 20));  // 8 MB  [B,H,T,D]
  short* Vtb = (short*)(ws + ((size_t)32 << 20));  // 8 MB  [B,H,D,T]
  short* Ob  = xb;                                 // alias: xb dead after QKV GEMMs
  float* Y   = (float*)d_out;

  k_prep<<<dim3(8192), dim3(256), 0, stream>>>(x, xb, Wq, Wk, Wv, Wo, Wt);
  k_qkv<<<dim3(768), dim3(256), 0, stream>>>(xb, Wt, bq, bk, bv, Qb, Kb, Vtb);
  k_attn<<<dim3(512), dim3(256), 0, stream>>>(Qb, Kb, Vtb, mask, Ob);
  k_proj<<<dim3(8, 64), dim3(256), 0, stream>>>(Ob, Wt + (size_t)3 * C_ * C_, bo, Y);
  k_ln<<<dim3(4096), dim3(256), 0, stream>>>(Y, lng, lnb);
}

// Round 6
// 186.868 us; speedup vs baseline: 1.6263x; 1.0677x over previous
//
#include <hip/hip_runtime.h>
#include <stdint.h>

#define B_ 4
#define T_ 1024
#define C_ 1024
#define H_ 16
#define D_ 64
#define M_ 4096   // B_*T_

typedef __attribute__((ext_vector_type(8))) short bf16x8;
typedef __attribute__((ext_vector_type(4))) float f32x4;
typedef __attribute__((ext_vector_type(4))) short short4v;

static __device__ __forceinline__ short f2bf(float f) {
  union { float f; unsigned u; } c; c.f = f;
  unsigned r = (c.u + 0x7fffu + ((c.u >> 16) & 1u)) >> 16;
  return (short)(unsigned short)r;
}

// async global->LDS, 16B per lane. LDS dest is wave-uniform base + lane*16.
static __device__ __forceinline__ void gl2lds16(const void* g, void* l) {
  __builtin_amdgcn_global_load_lds(
      (const __attribute__((address_space(1))) void*)(uintptr_t)g,
      (__attribute__((address_space(3))) void*)(uint32_t)(uintptr_t)l,
      16, 0, 0);
}

// ---------------- fused: cast x -> bf16  +  transpose-cast W -> Wt ----------------
__global__ __launch_bounds__(256) void k_prep(
    const float* __restrict__ x, short* __restrict__ xb,
    const float* __restrict__ Wq, const float* __restrict__ Wk,
    const float* __restrict__ Wv, const float* __restrict__ Wo,
    short* __restrict__ Wt) {
  __shared__ float t[32][33];
  const int id = blockIdx.x, tid = threadIdx.x;
  if (id < 4096) {
    int i = id * 256 + tid;
    float4 v = ((const float4*)x)[i];
    short4v o;
    o.x = f2bf(v.x); o.y = f2bf(v.y); o.z = f2bf(v.z); o.w = f2bf(v.w);
    ((short4v*)xb)[i] = o;
    return;
  }
  int j = id - 4096;
  int bz = j >> 10, r = j & 1023;
  int by = r >> 5, bx = r & 31;
  const float* W = (bz == 0) ? Wq : (bz == 1) ? Wk : (bz == 2) ? Wv : Wo;
  short* out = Wt + (size_t)bz * C_ * C_;
  int n0 = bx * 32, k0 = by * 32;
  int tx = tid & 31, ty = tid >> 5;
#pragma unroll
  for (int i = 0; i < 4; i++)
    t[ty + 8*i][tx] = W[(size_t)(k0 + ty + 8*i) * C_ + n0 + tx];
  __syncthreads();
#pragma unroll
  for (int i = 0; i < 4; i++)
    out[(size_t)(n0 + ty + 8*i) * C_ + k0 + tx] = f2bf(t[tx][ty + 8*i]);
}

// ---------------- bt-GEMM body: C[128x128] tile, BK=64, XOR-swizzled LDS ----------------
static __device__ __forceinline__ void gemm_body(const short* __restrict__ A,
                                                 const short* __restrict__ Bt,
                                                 short* sA, short* sB,
                                                 f32x4 acc[4][4], int m0, int n0) {
  const int tid = threadIdx.x;
  const int w = tid >> 6, lane = tid & 63;
  const int quad = lane >> 4, l16 = lane & 15;
  const int wm = (w >> 1) * 64, wn = (w & 1) * 64;
  const int srow = lane >> 3;          // row within 8-row chunk
  const int sch = lane & 7;            // stored 16B-chunk within row

#pragma unroll
  for (int mt = 0; mt < 4; mt++)
#pragma unroll
    for (int nt = 0; nt < 4; nt++)
#pragma unroll
      for (int e = 0; e < 4; e++) acc[mt][nt][e] = 0.f;

  for (int k0 = 0; k0 < C_; k0 += 64) {
    __syncthreads();
#pragma unroll
    for (int i = 0; i < 4; i++) {
      int c = w * 4 + i;               // 16 chunks of 1KB, 4 per wave
      int row = c * 8 + srow;
      int ch = sch ^ (row & 7);        // XOR swizzle
      gl2lds16(&A[(size_t)(m0 + row) * C_ + k0 + ch * 8], &sA[c * 512]);
      gl2lds16(&Bt[(size_t)(n0 + row) * C_ + k0 + ch * 8], &sB[c * 512]);
    }
    __syncthreads();
#pragma unroll
    for (int ks = 0; ks < 2; ks++) {
      bf16x8 af[4], bfv[4];
      int chq = ks * 4 + quad;
#pragma unroll
      for (int t4 = 0; t4 < 4; t4++) {
        int rowa = wm + t4 * 16 + l16;
        af[t4] = *(const bf16x8*)&sA[rowa * 64 + (chq ^ (rowa & 7)) * 8];
        int rowb = wn + t4 * 16 + l16;
        bfv[t4] = *(const bf16x8*)&sB[rowb * 64 + (chq ^ (rowb & 7)) * 8];
      }
#pragma unroll
      for (int mt = 0; mt < 4; mt++)
#pragma unroll
        for (int nt = 0; nt < 4; nt++)
          acc[mt][nt] = __builtin_amdgcn_mfma_f32_16x16x32_bf16(
              af[mt], bfv[nt], acc[mt][nt], 0, 0, 0);
    }
  }
}

// ---------------- QKV projection, mode-fastest 1-D grid, 3 blocks/CU ----------------
// id = mode + 3*bx + 24*by. All epilogues route through LDS for coalesced stores.
__global__ __launch_bounds__(256, 3) void k_qkv(
    const short* __restrict__ A, const short* __restrict__ WtAll,
    const float* __restrict__ bq, const float* __restrict__ bk,
    const float* __restrict__ bv,
    short* __restrict__ Qb, short* __restrict__ Kb, short* __restrict__ Vtb) {
  __shared__ short sU[17408];          // gemm: sA=sU[0:8192], sB=sU[8192:16384]
  const int id = blockIdx.x;
  const int mode = id % 3;
  const int j = id / 3;
  const int bx = j & 7, by = j >> 3;
  const int m0 = by * 128, n0 = bx * 128;
  const short* Bt = WtAll + (size_t)mode * C_ * C_;
  const float* bias = (mode == 0) ? bq : (mode == 1) ? bk : bv;
  f32x4 acc[4][4];
  gemm_body(A, Bt, sU, sU + 8192, acc, m0, n0);

  const int tid = threadIdx.x;
  const int w = tid >> 6, lane = tid & 63;
  const int quad = lane >> 4, l16 = lane & 15;
  const int wm = (w >> 1) * 64, wn = (w & 1) * 64;

  __syncthreads();   // all waves done with gemm LDS reads
  if (mode < 2) {
    // bf16 tile [m_local][n_local], stride 136 (pad 8), bias fused
#pragma unroll
    for (int nt = 0; nt < 4; nt++) {
      int nl = wn + nt * 16 + l16;
      float bval = bias[n0 + nl];
#pragma unroll
      for (int mt = 0; mt < 4; mt++)
#pragma unroll
        for (int r = 0; r < 4; r++)
          sU[(wm + mt * 16 + quad * 4 + r) * 136 + nl] = f2bf(acc[mt][nt][r] + bval);
    }
    __syncthreads();
    // coalesced copy: thread -> (row, head-half) = 64 shorts = 128B contiguous run
    int dr = tid >> 1, hf = tid & 1;
    int mg = m0 + dr;
    int bb = mg >> 10, t = mg & 1023;
    int h = (n0 >> 6) + hf;
    short* dst = (mode == 0) ? Qb : Kb;
    size_t base = ((((size_t)(bb * H_ + h)) << 10) + t) * D_;
#pragma unroll
    for (int i = 0; i < 8; i++)
      *(int4*)&dst[base + i * 8] = *(const int4*)&sU[dr * 136 + hf * 64 + i * 8];
  } else {
    // transposed bf16 tile: sU[n_local][m_local], stride 136 (pad 8)
#pragma unroll
    for (int nt = 0; nt < 4; nt++) {
      int nl = wn + nt * 16 + l16;
      float bval = bias[n0 + nl];
#pragma unroll
      for (int mt = 0; mt < 4; mt++)
#pragma unroll
        for (int r = 0; r < 4; r++)
          sU[nl * 136 + wm + mt * 16 + quad * 4 + r] = f2bf(acc[mt][nt][r] + bval);
    }
    __syncthreads();
    // copy out: thread -> half row (8 int4 = 128B contiguous along t)
    int dr = tid >> 1;
    int dg = n0 + dr, hd = dg >> 6, dl = dg & 63;
    int bb2 = m0 >> 10, t0 = m0 & 1023;
    size_t base = (((size_t)(bb2 * H_ + hd) * D_ + dl) << 10) + t0;
#pragma unroll
    for (int i = 0; i < 8; i++) {
      int jj = (tid & 1) * 8 + i;
      *(int4*)&Vtb[base + jj * 8] = *(const int4*)&sU[dr * 136 + jj * 8];
    }
  }
}

// ---------------- output projection: 64x128 tiles for 2 blocks/CU ----------------
__global__ __launch_bounds__(256) void k_proj(
    const short* __restrict__ A, const short* __restrict__ Bt,
    const float* __restrict__ bias, float* __restrict__ Y) {
  __shared__ short sA[4096];           // 64 x 64
  __shared__ short sB[8192];           // 128 x 64
  const int tid = threadIdx.x;
  const int w = tid >> 6, lane = tid & 63;
  const int quad = lane >> 4, l16 = lane & 15;
  const int m0 = blockIdx.y * 64, n0 = blockIdx.x * 128;
  const int wm = (w >> 1) * 32, wn = (w & 1) * 64;
  const int srow = lane >> 3, sch = lane & 7;

  f32x4 acc[2][4];
#pragma unroll
  for (int mt = 0; mt < 2; mt++)
#pragma unroll
    for (int nt = 0; nt < 4; nt++)
#pragma unroll
      for (int e = 0; e < 4; e++) acc[mt][nt][e] = 0.f;

  for (int k0 = 0; k0 < C_; k0 += 64) {
    __syncthreads();
#pragma unroll
    for (int i = 0; i < 6; i++) {      // 24 chunks of 1KB (8 A + 16 B), 6 per wave
      int c = w * 6 + i;
      if (c < 8) {
        int row = c * 8 + srow;
        int ch = sch ^ (row & 7);
        gl2lds16(&A[(size_t)(m0 + row) * C_ + k0 + ch * 8], &sA[c * 512]);
      } else {
        int c2 = c - 8;
        int row = c2 * 8 + srow;
        int ch = sch ^ (row & 7);
        gl2lds16(&Bt[(size_t)(n0 + row) * C_ + k0 + ch * 8], &sB[c2 * 512]);
      }
    }
    __syncthreads();
#pragma unroll
    for (int ks = 0; ks < 2; ks++) {
      bf16x8 af[2], bfv[4];
      int chq = ks * 4 + quad;
#pragma unroll
      for (int t2 = 0; t2 < 2; t2++) {
        int rowa = wm + t2 * 16 + l16;
        af[t2] = *(const bf16x8*)&sA[rowa * 64 + (chq ^ (rowa & 7)) * 8];
      }
#pragma unroll
      for (int t4 = 0; t4 < 4; t4++) {
        int rowb = wn + t4 * 16 + l16;
        bfv[t4] = *(const bf16x8*)&sB[rowb * 64 + (chq ^ (rowb & 7)) * 8];
      }
#pragma unroll
      for (int mt = 0; mt < 2; mt++)
#pragma unroll
        for (int nt = 0; nt < 4; nt++)
          acc[mt][nt] = __builtin_amdgcn_mfma_f32_16x16x32_bf16(
              af[mt], bfv[nt], acc[mt][nt], 0, 0, 0);
    }
  }

#pragma unroll
  for (int mt = 0; mt < 2; mt++)
#pragma unroll
    for (int nt = 0; nt < 4; nt++) {
      int ng = n0 + wn + nt * 16 + l16;
      float bval = bias[ng];
#pragma unroll
      for (int r = 0; r < 4; r++) {
        int mg = m0 + wm + mt * 16 + quad * 4 + r;
        Y[(size_t)mg * C_ + ng] = acc[mt][nt][r] + bval;
      }
    }
}

// ---------------- flash attention, LDS-staged, XCD-swizzled ----------------
#define PSTRIDE 136
__global__ __launch_bounds__(256, 2) void k_attn(
    const short* __restrict__ Qb, const short* __restrict__ Kb,
    const short* __restrict__ Vtb, const int* __restrict__ mask,
    short* __restrict__ Ob) {
  __shared__ short sK[8192];           // 128 x 64, swizzled
  __shared__ short sV[8192];           // 64 x 128, swizzled
  __shared__ short sP[4 * 32 * PSTRIDE];
  __shared__ float sBias[1024];
  const int tid = threadIdx.x;
  const int w = tid >> 6, lane = tid & 63;
  const int quad = lane >> 4, l16 = lane & 15;

  const int bx = blockIdx.x;
  const int xcd = bx & 7, j = bx >> 3;
  const int qb = j & 7, u = j >> 3;
  const int h = xcd * 2 + (u & 1), bb = u >> 1;
  const int tq0 = qb * 128 + w * 32;

  const short* Qh = Qb + ((size_t)(bb * H_ + h) << 10) * D_;    // [t][d]
  const short* Kh = Kb + ((size_t)(bb * H_ + h) << 10) * D_;    // [t][d]
  const short* Vh = Vtb + (((size_t)(bb * H_ + h) * D_) << 10); // [d][t]
  const int* mrow = mask + bb * T_;
  short* Pw = &sP[w * 32 * PSTRIDE];

  const float SC = 0.125f * 1.44269504088896340736f;  // 1/sqrt(D) * log2(e)

  {
    int4 m4 = ((const int4*)mrow)[tid];
    float4 bv4;
    bv4.x = m4.x ? 0.f : -1e30f; bv4.y = m4.y ? 0.f : -1e30f;
    bv4.z = m4.z ? 0.f : -1e30f; bv4.w = m4.w ? 0.f : -1e30f;
    ((float4*)sBias)[tid] = bv4;
  }

  bf16x8 aq[2][2];
#pragma unroll
  for (int rt = 0; rt < 2; rt++)
#pragma unroll
    for (int ks = 0; ks < 2; ks++)
      aq[rt][ks] = *(const bf16x8*)&Qh[(size_t)(tq0 + rt * 16 + l16) * D_ +
                                       ks * 32 + quad * 8];

  f32x4 o[2][4];
  float lsum[2][4];
#pragma unroll
  for (int rt = 0; rt < 2; rt++) {
#pragma unroll
    for (int nt = 0; nt < 4; nt++)
#pragma unroll
      for (int e = 0; e < 4; e++) o[rt][nt][e] = 0.f;
#pragma unroll
    for (int r = 0; r < 4; r++) lsum[rt][r] = 0.f;
  }

  for (int kt = 0; kt < T_; kt += 128) {
    __syncthreads();
#pragma unroll
    for (int i2 = 0; i2 < 4; i2++) {
      int i = w * 4 + i2;
      int row = i * 8 + (lane >> 3);
      int g = (lane & 7) ^ (row & 7);
      gl2lds16(&Kh[(size_t)(kt + row) * D_ + g * 8], &sK[i * 512]);
    }
#pragma unroll
    for (int i2 = 0; i2 < 4; i2++) {
      int i = w * 4 + i2;
      int row = i * 4 + (lane >> 4);
      int g = (lane & 15) ^ (row & 15);
      gl2lds16(&Vh[((size_t)row << 10) + kt + g * 8], &sV[i * 512]);
    }
    __syncthreads();

    f32x4 s[2][8];
#pragma unroll
    for (int rt = 0; rt < 2; rt++)
#pragma unroll
      for (int ct = 0; ct < 8; ct++)
#pragma unroll
        for (int e = 0; e < 4; e++) s[rt][ct][e] = 0.f;

#pragma unroll
    for (int ks = 0; ks < 2; ks++)
#pragma unroll
      for (int ct = 0; ct < 8; ct++) {
        int rowb = ct * 16 + l16;
        bf16x8 bk8 = *(const bf16x8*)&sK[rowb * 64 +
                                         (((ks * 4 + quad) ^ (rowb & 7)) * 8)];
        s[0][ct] = __builtin_amdgcn_mfma_f32_16x16x32_bf16(aq[0][ks], bk8, s[0][ct], 0, 0, 0);
        s[1][ct] = __builtin_amdgcn_mfma_f32_16x16x32_bf16(aq[1][ks], bk8, s[1][ct], 0, 0, 0);
      }

    float mb[8];
#pragma unroll
    for (int ct = 0; ct < 8; ct++) mb[ct] = sBias[kt + ct * 16 + l16];

#pragma unroll
    for (int rt = 0; rt < 2; rt++)
#pragma unroll
      for (int ct = 0; ct < 8; ct++)
#pragma unroll
        for (int r = 0; r < 4; r++) {
          float p = __builtin_amdgcn_exp2f(fmaf(s[rt][ct][r], SC, mb[ct]));
          lsum[rt][r] += p;
          Pw[(rt * 16 + quad * 4 + r) * PSTRIDE + ct * 16 + l16] = f2bf(p);
        }

#pragma unroll
    for (int ks2 = 0; ks2 < 4; ks2++) {
      bf16x8 pa0 = *(const bf16x8*)&Pw[l16 * PSTRIDE + ks2 * 32 + quad * 8];
      bf16x8 pa1 = *(const bf16x8*)&Pw[(16 + l16) * PSTRIDE + ks2 * 32 + quad * 8];
#pragma unroll
      for (int nt = 0; nt < 4; nt++) {
        int rowv = nt * 16 + l16;
        bf16x8 bv8 = *(const bf16x8*)&sV[rowv * 128 +
                                         (((ks2 * 4 + quad) ^ (rowv & 15)) * 8)];
        o[0][nt] = __builtin_amdgcn_mfma_f32_16x16x32_bf16(pa0, bv8, o[0][nt], 0, 0, 0);
        o[1][nt] = __builtin_amdgcn_mfma_f32_16x16x32_bf16(pa1, bv8, o[1][nt], 0, 0, 0);
      }
    }
  }

#pragma unroll
  for (int rt = 0; rt < 2; rt++)
#pragma unroll
    for (int r = 0; r < 4; r++) {
      float rs = lsum[rt][r];
#pragma unroll
      for (int off = 1; off < 16; off <<= 1) rs += __shfl_xor(rs, off);
      float inv = 1.f / rs;
      int tg = tq0 + rt * 16 + quad * 4 + r;
#pragma unroll
      for (int nt = 0; nt < 4; nt++) {
        int col = h * D_ + nt * 16 + l16;
        Ob[(size_t)(bb * T_ + tg) * C_ + col] = f2bf(o[rt][nt][r] * inv);
      }
    }
}

// ---------------- in-place LayerNorm over rows of 1024 ----------------
__global__ __launch_bounds__(256) void k_ln(float* __restrict__ Y,
                                            const float* __restrict__ g,
                                            const float* __restrict__ b) {
  __shared__ float red[4], red2[4];
  const int row = blockIdx.x, tid = threadIdx.x;
  float4* yp = (float4*)(Y + (size_t)row * C_);
  float4 v = yp[tid];
  float sm = v.x + v.y + v.z + v.w;
#pragma unroll
  for (int off = 32; off; off >>= 1) sm += __shfl_xor(sm, off);
  if ((tid & 63) == 0) red[tid >> 6] = sm;
  __syncthreads();
  float mu = (red[0] + red[1] + red[2] + red[3]) * (1.f / C_);
  float dx = v.x - mu, dy = v.y - mu, dz = v.z - mu, dw = v.w - mu;
  float q = dx * dx + dy * dy + dz * dz + dw * dw;
#pragma unroll
  for (int off = 32; off; off >>= 1) q += __shfl_xor(q, off);
  if ((tid & 63) == 0) red2[tid >> 6] = q;
  __syncthreads();
  float var = (red2[0] + red2[1] + red2[2] + red2[3]) * (1.f / C_);
  float rsq = rsqrtf(var + 1e-5f);
  float4 gg = ((const float4*)g)[tid];
  float4 bb = ((const float4*)b)[tid];
  float4 out;
  out.x = dx * rsq * gg.x + bb.x;
  out.y = dy * rsq * gg.y + bb.y;
  out.z = dz * rsq * gg.z + bb.z;
  out.w = dw * rsq * gg.w + bb.w;
  yp[tid] = out;
}

extern "C" void kernel_launch(void* const* d_in, const int* in_sizes, int n_in,
                              void* d_out, int out_size, void* d_ws, size_t ws_size,
                              hipStream_t stream) {
  (void)in_sizes; (void)n_in; (void)out_size; (void)ws_size;
  const float* x    = (const float*)d_in[0];
  const int*   mask = (const int*)d_in[1];
  const float* Wq   = (const float*)d_in[2];
  const float* bq   = (const float*)d_in[3];
  const float* Wk   = (const float*)d_in[4];
  const float* bk   = (const float*)d_in[5];
  const float* Wv   = (const float*)d_in[6];
  const float* bv   = (const float*)d_in[7];
  const float* Wo   = (const float*)d_in[8];
  const float* bo   = (const float*)d_in[9];
  const float* lng  = (const float*)d_in[10];
  const float* lnb  = (const float*)d_in[11];

  char* ws = (char*)d_ws;
  short* xb  = (short*)(ws);                       // 8 MB, reused as Ob after QKV
  short* Wt  = (short*)(ws + ((size_t)8  << 20));  // 8 MB: Wq^T,Wk^T,Wv^T,Wo^T bf16
  short* Qb  = (short*)(ws + ((size_t)16 << 20));  // 8 MB  [B,H,T,D]
  short* Kb  = (short*)(ws + ((size_t)24 << 20));  // 8 MB  [B,H,T,D]
  short* Vtb = (short*)(ws + ((size_t)32 << 20));  // 8 MB  [B,H,D,T]
  short* Ob  = xb;                                 // alias: xb dead after QKV GEMMs
  float* Y   = (float*)d_out;

  k_prep<<<dim3(8192), dim3(256), 0, stream>>>(x, xb, Wq, Wk, Wv, Wo, Wt);
  k_qkv<<<dim3(768), dim3(256), 0, stream>>>(xb, Wt, bq, bk, bv, Qb, Kb, Vtb);
  k_attn<<<dim3(512), dim3(256), 0, stream>>>(Qb, Kb, Vtb, mask, Ob);
  k_proj<<<dim3(8, 64), dim3(256), 0, stream>>>(Ob, Wt + (size_t)3 * C_ * C_, bo, Y);
  k_ln<<<dim3(4096), dim3(256), 0, stream>>>(Y, lng, lnb);
}